// Round 1
// 501.855 us; speedup vs baseline: 1.0043x; 1.0043x over previous
//
#include <hip/hip_runtime.h>
#include <hip/hip_bf16.h>

// Problem constants
#define S 128
#define BATCH 8192
#define E 300
#define KPAD 640            // 2E=600 padded to multiple of 64
#define H1 2048
#define H2 2048
#define CLS 1221
#define CPAD 1280           // padded N for last GEMM
#define PADTOK 1
#define VOCAB 100000

typedef __bf16 bf16x8 __attribute__((ext_vector_type(8)));
typedef float f32x16 __attribute__((ext_vector_type(16)));

__device__ __forceinline__ float b2f(ushort u) {
  union { unsigned int i; float f; } v; v.i = ((unsigned int)u) << 16; return v.f;
}
__device__ __forceinline__ ushort f2b(float f) {
  unsigned int i = __float_as_uint(f);
  unsigned int r = (i + 0x7FFFu + ((i >> 16) & 1u)) >> 16;
  return (ushort)r;
}
__device__ __forceinline__ void async16(const void* g, void* l) {
  __builtin_amdgcn_global_load_lds(
      (__attribute__((address_space(1))) void*)(void*)(const_cast<void*>(g)),
      (__attribute__((address_space(3))) void*)l, 16, 0, 0);
}

// ---------------------------------------------------------------------------
// Fused preprocessing: emb->bf16, W1->bf16 pad, W2->bf16, Wout->bf16 pad,
// x transpose. One quad (4 elements) per thread.
#define NQ_EMB (VOCAB * E / 4)          // 7,500,000
#define NQ_W1  (H1 * KPAD / 4)          // 327,680
#define NQ_W2  (H1 * H2 / 4)            // 1,048,576
#define NQ_WO  (CPAD * H2 / 4)          // 655,360
#define NQ_XT  (S * BATCH / 4)          // 262,144
#define NQ_TOT (NQ_EMB + NQ_W1 + NQ_W2 + NQ_WO + NQ_XT)

__global__ __launch_bounds__(256) void cvt_all(const float* __restrict__ Ein,
                                               ushort* __restrict__ Eb,
                                               const float* __restrict__ W1,
                                               ushort* __restrict__ W1p,
                                               const float* __restrict__ W2,
                                               ushort* __restrict__ W2b,
                                               const float* __restrict__ Wout,
                                               ushort* __restrict__ Woutp,
                                               const int* __restrict__ x,
                                               int* __restrict__ xT) {
  int q = blockIdx.x * 256 + threadIdx.x;
  if (q < NQ_EMB) {
    float4 v = ((const float4*)Ein)[q];
    ushort4 o;
    o.x = f2b(v.x); o.y = f2b(v.y); o.z = f2b(v.z); o.w = f2b(v.w);
    ((ushort4*)Eb)[q] = o;
    return;
  }
  q -= NQ_EMB;
  if (q < NQ_W1) {
    int row = q / 160;                 // 640/4 quads per padded row
    int k0 = (q - row * 160) * 4;
    ushort4 o; o.x = 0; o.y = 0; o.z = 0; o.w = 0;
    if (k0 < 2 * E) {
      float4 v = *(const float4*)(W1 + (size_t)row * (2 * E) + k0);
      o.x = f2b(v.x); o.y = f2b(v.y); o.z = f2b(v.z); o.w = f2b(v.w);
    }
    ((ushort4*)W1p)[q] = o;
    return;
  }
  q -= NQ_W1;
  if (q < NQ_W2) {
    float4 v = ((const float4*)W2)[q];
    ushort4 o;
    o.x = f2b(v.x); o.y = f2b(v.y); o.z = f2b(v.z); o.w = f2b(v.w);
    ((ushort4*)W2b)[q] = o;
    return;
  }
  q -= NQ_W2;
  if (q < NQ_WO) {
    int n = (q * 4) >> 11;             // row in padded [1280, 2048]
    ushort4 o; o.x = 0; o.y = 0; o.z = 0; o.w = 0;
    if (n < CLS) {
      float4 v = ((const float4*)Wout)[q];
      o.x = f2b(v.x); o.y = f2b(v.y); o.z = f2b(v.z); o.w = f2b(v.w);
    }
    ((ushort4*)Woutp)[q] = o;
    return;
  }
  q -= NQ_WO;
  if (q < NQ_XT) {
    int b = q >> 5;                    // 32 quads per sentence (128 tokens)
    int t4 = (q & 31) * 4;
    int4 o;
    o.x = x[(size_t)(t4 + 0) * BATCH + b];
    o.y = x[(size_t)(t4 + 1) * BATCH + b];
    o.z = x[(size_t)(t4 + 2) * BATCH + b];
    o.w = x[(size_t)(t4 + 3) * BATCH + b];
    ((int4*)xT)[q] = o;
  }
}

// ---------------------------------------------------------------------------
// Stage 1: embedding gather + first-token + masked mean -> feat [B, 640] bf16
// One block (128 threads = 2 waves) per sentence; emb is the bf16 copy.
// MLP-maximizing layout: each WAVE owns alternate tokens at 8 B/lane
// (ushort4). Per token: one 64-lane 512 B load + one 11-lane 88 B tail load.
// Unroll x8 tokens/wave -> ~4.8 KB in flight per wave (~5x the old ushort2
// scheme, which measured 45% of HBM peak = classic Little's-law shortfall).
// Cross-wave partial-sum combine via 1.2 KB LDS at the end.
__global__ __launch_bounds__(128) void embed_kernel(const int* __restrict__ xT,
                                                    const ushort* __restrict__ emb,
                                                    ushort* __restrict__ feat) {
  __shared__ uint offs[S];
  __shared__ unsigned long long masks[2];
  __shared__ __align__(16) float part[76 * 4];   // wave1 partials: 75 chunks x4
  const int b = blockIdx.x;
  const int t = threadIdx.x;

  int tok = xT[b * S + t];             // coalesced
  offs[t] = (uint)tok * 600u;          // byte offset into bf16 emb table
  unsigned long long m = __ballot(tok != PADTOK);
  if ((t & 63) == 0) masks[t >> 6] = m;
  __syncthreads();

  unsigned long long m0 = masks[0], m1 = masks[1];
  int last;
  if (m1)      last = 127 - __clzll(m1);
  else if (m0) last = 63 - __clzll(m0);
  else         last = S - 1;           // all-pad: ref argmax gives last=S-1
  const int n = last + 1;
  const float inv = 1.0f / (float)n;

  const int w = t >> 6;                // wave id: wave0 even tokens, wave1 odd
  const int lane = t & 63;
  const char* base = (const char*)emb;
  const uint off0 = (uint)lane * 8u;   // chunk byte offset within row (0..511)
  const bool tail = (lane < 11);       // chunks 64..74 cover bytes 512..599
  const uint off1 = 512u + (uint)lane * 8u;

  float a0 = 0.f, a1 = 0.f, a2 = 0.f, a3 = 0.f;   // chunk `lane`
  float c0 = 0.f, c1 = 0.f, c2 = 0.f, c3 = 0.f;   // chunk 64+lane (tail lanes)

  int s = w;
  // main loop: 8 tokens per wave per iteration (16-token span)
  for (; s + 14 < n; s += 16) {
    uint o[8];
#pragma unroll
    for (int j = 0; j < 8; j++) o[j] = offs[s + 2 * j];
    ushort4 u[8];
#pragma unroll
    for (int j = 0; j < 8; j++) u[j] = *(const ushort4*)(base + (o[j] + off0));
    ushort4 v[8];
    if (tail) {
#pragma unroll
      for (int j = 0; j < 8; j++) v[j] = *(const ushort4*)(base + (o[j] + off1));
    }
#pragma unroll
    for (int j = 0; j < 8; j++) {
      a0 += b2f(u[j].x); a1 += b2f(u[j].y);
      a2 += b2f(u[j].z); a3 += b2f(u[j].w);
    }
    if (tail) {
#pragma unroll
      for (int j = 0; j < 8; j++) {
        c0 += b2f(v[j].x); c1 += b2f(v[j].y);
        c2 += b2f(v[j].z); c3 += b2f(v[j].w);
      }
    }
  }
  for (; s < n; s += 2) {
    uint o = offs[s];
    ushort4 u = *(const ushort4*)(base + (o + off0));
    a0 += b2f(u.x); a1 += b2f(u.y); a2 += b2f(u.z); a3 += b2f(u.w);
    if (tail) {
      ushort4 v = *(const ushort4*)(base + (o + off1));
      c0 += b2f(v.x); c1 += b2f(v.y); c2 += b2f(v.z); c3 += b2f(v.w);
    }
  }

  // cross-wave combine: wave1 publishes partials, wave0 reduces + stores mean
  if (w == 1) {
    float4 av; av.x = a0; av.y = a1; av.z = a2; av.w = a3;
    *(float4*)&part[lane * 4] = av;
    if (tail) {
      float4 cv; cv.x = c0; cv.y = c1; cv.z = c2; cv.w = c3;
      *(float4*)&part[(64 + lane) * 4] = cv;
    }
  }
  __syncthreads();

  ushort* fr = feat + (size_t)b * KPAD;
  if (w == 0) {
    float4 pv = *(const float4*)&part[lane * 4];
    ushort4 mo;
    mo.x = f2b((a0 + pv.x) * inv); mo.y = f2b((a1 + pv.y) * inv);
    mo.z = f2b((a2 + pv.z) * inv); mo.w = f2b((a3 + pv.w) * inv);
    *(ushort4*)(fr + E + lane * 4) = mo;           // byte 600+8*lane, aligned
    if (tail) {
      float4 qv = *(const float4*)&part[(64 + lane) * 4];
      ushort4 mo2;
      mo2.x = f2b((c0 + qv.x) * inv); mo2.y = f2b((c1 + qv.y) * inv);
      mo2.z = f2b((c2 + qv.z) * inv); mo2.w = f2b((c3 + qv.w) * inv);
      *(ushort4*)(fr + E + (64 + lane) * 4) = mo2;
    }
  }

  // first-token half: direct bf16 copy (75 threads x 8 B = 600 B)
  const uint o0 = offs[0];
  if (t < 75) {
    *(ushort4*)(fr + 4 * t) = *(const ushort4*)(base + (o0 + 8u * (uint)t));
  } else if (t < 85) {
    // zero the K padding 600..639 (10 threads x 4 elems)
    ushort4 z; z.x = 0; z.y = 0; z.z = 0; z.w = 0;
    *(ushort4*)(fr + 2 * E + 4 * (t - 75)) = z;
  }
}

// ---------------------------------------------------------------------------
// GEMM: C[M,N] = act(A[M,K] * B[N,K]^T + bias), A/B bf16, fp32 MFMA accum.
// 128x128 tile, BK=64, 256 threads (4 waves, 2x2 of 64x64), 32x32x16 MFMA.
// LDS layout XOR-swizzled at 16B-chunk granularity via the global_load_lds
// source mapping: slot(row,kc) = row*8 + (kc ^ (row&7)) -> conflict-free
// ds_read_b128 (each quarter-wave tiles all 32 banks exactly 4x = minimum).
#define BM 128
#define BN 128
#define BK 64

template <bool RELU, bool NGUARD, bool FP32OUT>
__global__ __launch_bounds__(256) void gemm_bt(const ushort* __restrict__ A,
                                               const ushort* __restrict__ B,
                                               const float* __restrict__ bias,
                                               void* __restrict__ Cv,
                                               int K, int lda, int ldb, int ldc,
                                               int Nreal) {
  __shared__ __align__(16) ushort lA[BM * BK];  // 16 KB
  __shared__ __align__(16) ushort lB[BN * BK];  // 16 KB

  const int tid = threadIdx.x;
  const int wave = tid >> 6;
  const int lane = tid & 63;
  const int m0 = blockIdx.y * BM;
  const int n0 = blockIdx.x * BN;
  const int wm = (wave >> 1) * 64;   // wave sub-tile origin in tile
  const int wn = (wave & 1) * 64;

  f32x16 acc[2][2];
#pragma unroll
  for (int i = 0; i < 2; i++)
#pragma unroll
    for (int j = 0; j < 2; j++)
#pragma unroll
      for (int r = 0; r < 16; r++) acc[i][j][r] = 0.f;

  // staging: 16 instrs of 64 slots (8 rows x 8 chunks each); wave does 4.
  // slot i in group: row = g*8 + (i>>3), chunk c = i&7, kc = c ^ (row&7).
  const int srow8 = lane >> 3;                 // row within 8-row group
  const int kcw = (lane & 7) ^ srow8;          // swizzled source k-chunk

  // fragment read geometry (32x32x16): row = lane&31, k = (lane>>5)*8 + j
  const int lr = lane & 31;
  const int lk = lane >> 5;                    // 0/1
  const int lx = lr & 7;                       // for swizzle

  for (int k0 = 0; k0 < K; k0 += BK) {
#pragma unroll
    for (int j = 0; j < 4; j++) {
      const int g = wave * 4 + j;
      const int row = g * 8 + srow8;
      async16(A + (size_t)(m0 + row) * lda + k0 + kcw * 8, (void*)&lA[g * 512]);
      async16(B + (size_t)(n0 + row) * ldb + k0 + kcw * 8, (void*)&lB[g * 512]);
    }
    __syncthreads();

#pragma unroll
    for (int ks = 0; ks < 4; ks++) {
      const int kc = ks * 2 + lk;
      bf16x8 af[2], bfr[2];
#pragma unroll
      for (int mi = 0; mi < 2; mi++) {
        const int row = wm + mi * 32 + lr;
        af[mi] = *(const bf16x8*)&lA[(row * 8 + (kc ^ lx)) * 8];
      }
#pragma unroll
      for (int ni = 0; ni < 2; ni++) {
        const int row = wn + ni * 32 + lr;
        bfr[ni] = *(const bf16x8*)&lB[(row * 8 + (kc ^ lx)) * 8];
      }
#pragma unroll
      for (int mi = 0; mi < 2; mi++)
#pragma unroll
        for (int ni = 0; ni < 2; ni++)
          acc[mi][ni] = __builtin_amdgcn_mfma_f32_32x32x16_bf16(
              af[mi], bfr[ni], acc[mi][ni], 0, 0, 0);
    }
    __syncthreads();
  }

  // Epilogue. 32x32 C/D layout: col = lane&31,
  // row = (reg&3) + 8*(reg>>2) + 4*(lane>>5)   [verified m74/m101]
#pragma unroll
  for (int ni = 0; ni < 2; ni++) {
    const int col = n0 + wn + ni * 32 + lr;
    const bool ok = (!NGUARD) || (col < Nreal);
    const float bv = ok ? bias[col] : 0.f;
#pragma unroll
    for (int mi = 0; mi < 2; mi++) {
#pragma unroll
      for (int r = 0; r < 16; r++) {
        const int row = m0 + wm + mi * 32 + (r & 3) + 8 * (r >> 2) + 4 * lk;
        float v = acc[mi][ni][r] + bv;
        if (RELU) v = fmaxf(v, 0.f);
        if (ok) {
          if (FP32OUT) ((float*)Cv)[(size_t)row * ldc + col] = v;
          else         ((ushort*)Cv)[(size_t)row * ldc + col] = f2b(v);
        }
      }
    }
  }
}

// ---------------------------------------------------------------------------
extern "C" void kernel_launch(void* const* d_in, const int* in_sizes, int n_in,
                              void* d_out, int out_size, void* d_ws, size_t ws_size,
                              hipStream_t stream) {
  const int* x = (const int*)d_in[0];
  const float* emb = (const float*)d_in[1];
  const float* W1 = (const float*)d_in[2];
  const float* b1 = (const float*)d_in[3];
  const float* W2 = (const float*)d_in[4];
  const float* b2 = (const float*)d_in[5];
  const float* Wout = (const float*)d_in[6];
  const float* bout = (const float*)d_in[7];
  float* out = (float*)d_out;

  char* ws = (char*)d_ws;
  ushort* feat = (ushort*)ws;  ws += (size_t)BATCH * KPAD * 2;   // 10.5 MB
  ushort* h1 = (ushort*)ws;    ws += (size_t)BATCH * H1 * 2;     // 33.6 MB
  ushort* h2 = (ushort*)ws;    ws += (size_t)BATCH * H2 * 2;     // 33.6 MB
  ushort* W1p = (ushort*)ws;   ws += (size_t)H1 * KPAD * 2;      // 2.6 MB
  ushort* W2b = (ushort*)ws;   ws += (size_t)H2 * H1 * 2;        // 8.4 MB
  ushort* Woutp = (ushort*)ws; ws += (size_t)CPAD * H2 * 2;      // 5.2 MB
  ushort* Eb = (ushort*)ws;    ws += (size_t)VOCAB * E * 2;      // 60 MB
  int* xT = (int*)ws;          ws += (size_t)S * BATCH * 4;      // 4 MB

  cvt_all<<<(NQ_TOT + 255) / 256, 256, 0, stream>>>(emb, Eb, W1, W1p, W2, W2b,
                                                    Wout, Woutp, x, xT);
  embed_kernel<<<BATCH, S, 0, stream>>>(xT, Eb, feat);

  // L1: feat[8192,640] x W1p[2048,640]^T -> relu -> h1[8192,2048] bf16
  gemm_bt<true, false, false><<<dim3(H1 / BN, BATCH / BM), 256, 0, stream>>>(
      feat, W1p, b1, (void*)h1, KPAD, KPAD, KPAD, H1, H1);
  // L2: h1 x W2b[2048,2048]^T -> relu -> h2 bf16
  gemm_bt<true, false, false><<<dim3(H2 / BN, BATCH / BM), 256, 0, stream>>>(
      h1, W2b, b2, (void*)h2, H1, H1, H1, H2, H2);
  // L3: h2 x Woutp[1280,2048]^T + bias -> out[8192,1221] fp32 (guarded)
  gemm_bt<false, true, true><<<dim3(CPAD / BN, BATCH / BM), 256, 0, stream>>>(
      h2, Woutp, bout, (void*)out, H2, H2, H2, CLS, CLS);
}

// Round 2
// 493.687 us; speedup vs baseline: 1.0210x; 1.0165x over previous
//
#include <hip/hip_runtime.h>
#include <hip/hip_bf16.h>

// Problem constants
#define S 128
#define BATCH 8192
#define E 300
#define KPAD 640            // 2E=600 padded to multiple of 64
#define H1 2048
#define H2 2048
#define CLS 1221
#define CPAD 1280           // padded N for last GEMM
#define PADTOK 1
#define VOCAB 100000

typedef __bf16 bf16x8 __attribute__((ext_vector_type(8)));
typedef float f32x4 __attribute__((ext_vector_type(4)));

__device__ __forceinline__ float b2f(ushort u) {
  union { unsigned int i; float f; } v; v.i = ((unsigned int)u) << 16; return v.f;
}
__device__ __forceinline__ ushort f2b(float f) {
  unsigned int i = __float_as_uint(f);
  unsigned int r = (i + 0x7FFFu + ((i >> 16) & 1u)) >> 16;
  return (ushort)r;
}
__device__ __forceinline__ void async16(const void* g, void* l) {
  __builtin_amdgcn_global_load_lds(
      (__attribute__((address_space(1))) void*)(void*)(const_cast<void*>(g)),
      (__attribute__((address_space(3))) void*)l, 16, 0, 0);
}

// ---------------------------------------------------------------------------
// Fused preprocessing: emb->bf16, W1->bf16 pad, W2->bf16, Wout->bf16 pad,
// x transpose. One quad (4 elements) per thread.
#define NQ_EMB (VOCAB * E / 4)          // 7,500,000
#define NQ_W1  (H1 * KPAD / 4)          // 327,680
#define NQ_W2  (H1 * H2 / 4)            // 1,048,576
#define NQ_WO  (CPAD * H2 / 4)          // 655,360
#define NQ_XT  (S * BATCH / 4)          // 262,144
#define NQ_TOT (NQ_EMB + NQ_W1 + NQ_W2 + NQ_WO + NQ_XT)

__global__ __launch_bounds__(256) void cvt_all(const float* __restrict__ Ein,
                                               ushort* __restrict__ Eb,
                                               const float* __restrict__ W1,
                                               ushort* __restrict__ W1p,
                                               const float* __restrict__ W2,
                                               ushort* __restrict__ W2b,
                                               const float* __restrict__ Wout,
                                               ushort* __restrict__ Woutp,
                                               const int* __restrict__ x,
                                               int* __restrict__ xT) {
  int q = blockIdx.x * 256 + threadIdx.x;
  if (q < NQ_EMB) {
    float4 v = ((const float4*)Ein)[q];
    ushort4 o;
    o.x = f2b(v.x); o.y = f2b(v.y); o.z = f2b(v.z); o.w = f2b(v.w);
    ((ushort4*)Eb)[q] = o;
    return;
  }
  q -= NQ_EMB;
  if (q < NQ_W1) {
    int row = q / 160;                 // 640/4 quads per padded row
    int k0 = (q - row * 160) * 4;
    ushort4 o; o.x = 0; o.y = 0; o.z = 0; o.w = 0;
    if (k0 < 2 * E) {
      float4 v = *(const float4*)(W1 + (size_t)row * (2 * E) + k0);
      o.x = f2b(v.x); o.y = f2b(v.y); o.z = f2b(v.z); o.w = f2b(v.w);
    }
    ((ushort4*)W1p)[q] = o;
    return;
  }
  q -= NQ_W1;
  if (q < NQ_W2) {
    float4 v = ((const float4*)W2)[q];
    ushort4 o;
    o.x = f2b(v.x); o.y = f2b(v.y); o.z = f2b(v.z); o.w = f2b(v.w);
    ((ushort4*)W2b)[q] = o;
    return;
  }
  q -= NQ_W2;
  if (q < NQ_WO) {
    int n = (q * 4) >> 11;             // row in padded [1280, 2048]
    ushort4 o; o.x = 0; o.y = 0; o.z = 0; o.w = 0;
    if (n < CLS) {
      float4 v = ((const float4*)Wout)[q];
      o.x = f2b(v.x); o.y = f2b(v.y); o.z = f2b(v.z); o.w = f2b(v.w);
    }
    ((ushort4*)Woutp)[q] = o;
    return;
  }
  q -= NQ_WO;
  if (q < NQ_XT) {
    int b = q >> 5;                    // 32 quads per sentence (128 tokens)
    int t4 = (q & 31) * 4;
    int4 o;
    o.x = x[(size_t)(t4 + 0) * BATCH + b];
    o.y = x[(size_t)(t4 + 1) * BATCH + b];
    o.z = x[(size_t)(t4 + 2) * BATCH + b];
    o.w = x[(size_t)(t4 + 3) * BATCH + b];
    ((int4*)xT)[q] = o;
  }
}

// ---------------------------------------------------------------------------
// Stage 1: embedding gather + first-token + masked mean -> feat [B, 640] bf16
// One block (128 threads = 2 waves) per sentence; emb is the bf16 copy.
// Gather is random-access-bound (~360 MB HBM @ ~3.6 TB/s); kept as-is.
__global__ __launch_bounds__(128) void embed_kernel(const int* __restrict__ xT,
                                                    const ushort* __restrict__ emb,
                                                    ushort* __restrict__ feat) {
  __shared__ uint offs[S];
  __shared__ unsigned long long masks[2];
  __shared__ __align__(16) float part[76 * 4];   // wave1 partials: 75 chunks x4
  const int b = blockIdx.x;
  const int t = threadIdx.x;

  int tok = xT[b * S + t];             // coalesced
  offs[t] = (uint)tok * 600u;          // byte offset into bf16 emb table
  unsigned long long m = __ballot(tok != PADTOK);
  if ((t & 63) == 0) masks[t >> 6] = m;
  __syncthreads();

  unsigned long long m0 = masks[0], m1 = masks[1];
  int last;
  if (m1)      last = 127 - __clzll(m1);
  else if (m0) last = 63 - __clzll(m0);
  else         last = S - 1;           // all-pad: ref argmax gives last=S-1
  const int n = last + 1;
  const float inv = 1.0f / (float)n;

  const int w = t >> 6;                // wave id: wave0 even tokens, wave1 odd
  const int lane = t & 63;
  const char* base = (const char*)emb;
  const uint off0 = (uint)lane * 8u;   // chunk byte offset within row (0..511)
  const bool tail = (lane < 11);       // chunks 64..74 cover bytes 512..599
  const uint off1 = 512u + (uint)lane * 8u;

  float a0 = 0.f, a1 = 0.f, a2 = 0.f, a3 = 0.f;   // chunk `lane`
  float c0 = 0.f, c1 = 0.f, c2 = 0.f, c3 = 0.f;   // chunk 64+lane (tail lanes)

  int s = w;
  // main loop: 8 tokens per wave per iteration (16-token span)
  for (; s + 14 < n; s += 16) {
    uint o[8];
#pragma unroll
    for (int j = 0; j < 8; j++) o[j] = offs[s + 2 * j];
    ushort4 u[8];
#pragma unroll
    for (int j = 0; j < 8; j++) u[j] = *(const ushort4*)(base + (o[j] + off0));
    ushort4 v[8];
    if (tail) {
#pragma unroll
      for (int j = 0; j < 8; j++) v[j] = *(const ushort4*)(base + (o[j] + off1));
    }
#pragma unroll
    for (int j = 0; j < 8; j++) {
      a0 += b2f(u[j].x); a1 += b2f(u[j].y);
      a2 += b2f(u[j].z); a3 += b2f(u[j].w);
    }
    if (tail) {
#pragma unroll
      for (int j = 0; j < 8; j++) {
        c0 += b2f(v[j].x); c1 += b2f(v[j].y);
        c2 += b2f(v[j].z); c3 += b2f(v[j].w);
      }
    }
  }
  for (; s < n; s += 2) {
    uint o = offs[s];
    ushort4 u = *(const ushort4*)(base + (o + off0));
    a0 += b2f(u.x); a1 += b2f(u.y); a2 += b2f(u.z); a3 += b2f(u.w);
    if (tail) {
      ushort4 v = *(const ushort4*)(base + (o + off1));
      c0 += b2f(v.x); c1 += b2f(v.y); c2 += b2f(v.z); c3 += b2f(v.w);
    }
  }

  // cross-wave combine: wave1 publishes partials, wave0 reduces + stores mean
  if (w == 1) {
    float4 av; av.x = a0; av.y = a1; av.z = a2; av.w = a3;
    *(float4*)&part[lane * 4] = av;
    if (tail) {
      float4 cv; cv.x = c0; cv.y = c1; cv.z = c2; cv.w = c3;
      *(float4*)&part[(64 + lane) * 4] = cv;
    }
  }
  __syncthreads();

  ushort* fr = feat + (size_t)b * KPAD;
  if (w == 0) {
    float4 pv = *(const float4*)&part[lane * 4];
    ushort4 mo;
    mo.x = f2b((a0 + pv.x) * inv); mo.y = f2b((a1 + pv.y) * inv);
    mo.z = f2b((a2 + pv.z) * inv); mo.w = f2b((a3 + pv.w) * inv);
    *(ushort4*)(fr + E + lane * 4) = mo;           // byte 600+8*lane, aligned
    if (tail) {
      float4 qv = *(const float4*)&part[(64 + lane) * 4];
      ushort4 mo2;
      mo2.x = f2b((c0 + qv.x) * inv); mo2.y = f2b((c1 + qv.y) * inv);
      mo2.z = f2b((c2 + qv.z) * inv); mo2.w = f2b((c3 + qv.w) * inv);
      *(ushort4*)(fr + E + (64 + lane) * 4) = mo2;
    }
  }

  // first-token half: direct bf16 copy (75 threads x 8 B = 600 B)
  const uint o0 = offs[0];
  if (t < 75) {
    *(ushort4*)(fr + 4 * t) = *(const ushort4*)(base + (o0 + 8u * (uint)t));
  } else if (t < 85) {
    // zero the K padding 600..639 (10 threads x 4 elems)
    ushort4 z; z.x = 0; z.y = 0; z.z = 0; z.w = 0;
    *(ushort4*)(fr + 2 * E + 4 * (t - 75)) = z;
  }
}

// ---------------------------------------------------------------------------
// GEMM: C[M,N] = act(A[M,K] * B[N,K]^T + bias), A/B bf16, fp32 MFMA accum.
// 128x128 tile, BK=64, 256 threads (4 waves, 2x2 of 64x64 sub-tiles).
// Inner decomposition: 4x4 of 16x16x32 MFMA per wave (m97 geometry).
// Rationale: the previous 2x2-of-32x32 issued 1 ds_read_b128 per MFMA
// (LDS-read bound, MfmaUtil 26%); 4x4-of-16x16 reuses each fragment 4x:
// 16 reads per 32 MFMA -> 2.3x lower LDS pressure (m97: 874-912 TF).
// LDS layout XOR-swizzled at 16B-chunk granularity via the global_load_lds
// source mapping: slot(row,kc) = row*8 + (kc ^ (row&7)) -> conflict-free
// ds_read_b128 (16-lane groups spread over all 32 banks, 2-way max).
#define BM 128
#define BN 128
#define BK 64

template <bool RELU, bool NGUARD, bool FP32OUT>
__global__ __launch_bounds__(256) void gemm_bt(const ushort* __restrict__ A,
                                               const ushort* __restrict__ B,
                                               const float* __restrict__ bias,
                                               void* __restrict__ Cv,
                                               int K, int lda, int ldb, int ldc,
                                               int Nreal) {
  __shared__ __align__(16) ushort lA[BM * BK];  // 16 KB
  __shared__ __align__(16) ushort lB[BN * BK];  // 16 KB

  const int tid = threadIdx.x;
  const int wave = tid >> 6;
  const int lane = tid & 63;
  const int m0 = blockIdx.y * BM;
  const int n0 = blockIdx.x * BN;
  const int wm = (wave >> 1) * 64;   // wave sub-tile origin in tile
  const int wn = (wave & 1) * 64;

  f32x4 acc[4][4];
#pragma unroll
  for (int i = 0; i < 4; i++)
#pragma unroll
    for (int j = 0; j < 4; j++)
#pragma unroll
      for (int r = 0; r < 4; r++) acc[i][j][r] = 0.f;

  // staging: 16 instrs of 64 slots (8 rows x 8 chunks each); wave does 4.
  // slot i in group: row = g*8 + (i>>3), chunk c = i&7, kc = c ^ (row&7).
  const int srow8 = lane >> 3;                 // row within 8-row group
  const int kcw = (lane & 7) ^ srow8;          // swizzled source k-chunk

  // fragment read geometry (16x16x32): row = lane&15, k = (lane>>4)*8 + j
  const int fr = lane & 15;                    // row within 16-row fragment
  const int fq = lane >> 4;                    // 0..3 -> k-subchunk

  for (int k0 = 0; k0 < K; k0 += BK) {
#pragma unroll
    for (int j = 0; j < 4; j++) {
      const int g = wave * 4 + j;
      const int row = g * 8 + srow8;
      async16(A + (size_t)(m0 + row) * lda + k0 + kcw * 8, (void*)&lA[g * 512]);
      async16(B + (size_t)(n0 + row) * ldb + k0 + kcw * 8, (void*)&lB[g * 512]);
    }
    __syncthreads();

#pragma unroll
    for (int ks = 0; ks < 2; ks++) {           // two K=32 halves of BK=64
      const int kc = ks * 4 + fq;              // k-chunk 0..7
      bf16x8 af[4], bfr[4];
#pragma unroll
      for (int mi = 0; mi < 4; mi++) {
        const int row = wm + mi * 16 + fr;
        af[mi] = *(const bf16x8*)&lA[(row * 8 + (kc ^ (row & 7))) * 8];
      }
#pragma unroll
      for (int ni = 0; ni < 4; ni++) {
        const int row = wn + ni * 16 + fr;
        bfr[ni] = *(const bf16x8*)&lB[(row * 8 + (kc ^ (row & 7))) * 8];
      }
#pragma unroll
      for (int mi = 0; mi < 4; mi++)
#pragma unroll
        for (int ni = 0; ni < 4; ni++)
          acc[mi][ni] = __builtin_amdgcn_mfma_f32_16x16x32_bf16(
              af[mi], bfr[ni], acc[mi][ni], 0, 0, 0);
    }
    __syncthreads();
  }

  // Epilogue. 16x16 C/D layout: col = lane&15, row = (lane>>4)*4 + reg
  // [verified m89/m91]
#pragma unroll
  for (int ni = 0; ni < 4; ni++) {
    const int col = n0 + wn + ni * 16 + fr;
    const bool ok = (!NGUARD) || (col < Nreal);
    const float bv = ok ? bias[col] : 0.f;
#pragma unroll
    for (int mi = 0; mi < 4; mi++) {
      const int rbase = m0 + wm + mi * 16 + fq * 4;
#pragma unroll
      for (int r = 0; r < 4; r++) {
        const int row = rbase + r;
        float v = acc[mi][ni][r] + bv;
        if (RELU) v = fmaxf(v, 0.f);
        if (ok) {
          if (FP32OUT) ((float*)Cv)[(size_t)row * ldc + col] = v;
          else         ((ushort*)Cv)[(size_t)row * ldc + col] = f2b(v);
        }
      }
    }
  }
}

// ---------------------------------------------------------------------------
extern "C" void kernel_launch(void* const* d_in, const int* in_sizes, int n_in,
                              void* d_out, int out_size, void* d_ws, size_t ws_size,
                              hipStream_t stream) {
  const int* x = (const int*)d_in[0];
  const float* emb = (const float*)d_in[1];
  const float* W1 = (const float*)d_in[2];
  const float* b1 = (const float*)d_in[3];
  const float* W2 = (const float*)d_in[4];
  const float* b2 = (const float*)d_in[5];
  const float* Wout = (const float*)d_in[6];
  const float* bout = (const float*)d_in[7];
  float* out = (float*)d_out;

  char* ws = (char*)d_ws;
  ushort* feat = (ushort*)ws;  ws += (size_t)BATCH * KPAD * 2;   // 10.5 MB
  ushort* h1 = (ushort*)ws;    ws += (size_t)BATCH * H1 * 2;     // 33.6 MB
  ushort* h2 = (ushort*)ws;    ws += (size_t)BATCH * H2 * 2;     // 33.6 MB
  ushort* W1p = (ushort*)ws;   ws += (size_t)H1 * KPAD * 2;      // 2.6 MB
  ushort* W2b = (ushort*)ws;   ws += (size_t)H2 * H1 * 2;        // 8.4 MB
  ushort* Woutp = (ushort*)ws; ws += (size_t)CPAD * H2 * 2;      // 5.2 MB
  ushort* Eb = (ushort*)ws;    ws += (size_t)VOCAB * E * 2;      // 60 MB
  int* xT = (int*)ws;          ws += (size_t)S * BATCH * 4;      // 4 MB

  cvt_all<<<(NQ_TOT + 255) / 256, 256, 0, stream>>>(emb, Eb, W1, W1p, W2, W2b,
                                                    Wout, Woutp, x, xT);
  embed_kernel<<<BATCH, S, 0, stream>>>(xT, Eb, feat);

  // L1: feat[8192,640] x W1p[2048,640]^T -> relu -> h1[8192,2048] bf16
  gemm_bt<true, false, false><<<dim3(H1 / BN, BATCH / BM), 256, 0, stream>>>(
      feat, W1p, b1, (void*)h1, KPAD, KPAD, KPAD, H1, H1);
  // L2: h1 x W2b[2048,2048]^T -> relu -> h2 bf16
  gemm_bt<true, false, false><<<dim3(H2 / BN, BATCH / BM), 256, 0, stream>>>(
      h1, W2b, b2, (void*)h2, H1, H1, H1, H2, H2);
  // L3: h2 x Woutp[1280,2048]^T + bias -> out[8192,1221] fp32 (guarded)
  gemm_bt<false, true, true><<<dim3(CPAD / BN, BATCH / BM), 256, 0, stream>>>(
      h2, Woutp, bout, (void*)out, H2, H2, H2, CLS, CLS);
}

// Round 4
// 492.541 us; speedup vs baseline: 1.0233x; 1.0023x over previous
//
#include <hip/hip_runtime.h>
#include <hip/hip_bf16.h>

// Problem constants
#define S 128
#define BATCH 8192
#define E 300
#define KPAD 640            // 2E=600 padded to multiple of 64
#define H1 2048
#define H2 2048
#define CLS 1221
#define CPAD 1280           // padded N for last GEMM
#define PADTOK 1
#define VOCAB 100000

typedef __bf16 bf16x8 __attribute__((ext_vector_type(8)));
typedef float f32x4 __attribute__((ext_vector_type(4)));

__device__ __forceinline__ float b2f(ushort u) {
  union { unsigned int i; float f; } v; v.i = ((unsigned int)u) << 16; return v.f;
}
__device__ __forceinline__ ushort f2b(float f) {
  unsigned int i = __float_as_uint(f);
  unsigned int r = (i + 0x7FFFu + ((i >> 16) & 1u)) >> 16;
  return (ushort)r;
}
__device__ __forceinline__ void async16(const void* g, void* l) {
  __builtin_amdgcn_global_load_lds(
      (__attribute__((address_space(1))) void*)(void*)(const_cast<void*>(g)),
      (__attribute__((address_space(3))) void*)l, 16, 0, 0);
}

// ---------------------------------------------------------------------------
// Fused preprocessing: emb->bf16, W1->bf16 pad, W2->bf16, Wout->bf16 pad,
// x transpose. One quad (4 elements) per thread.
#define NQ_EMB (VOCAB * E / 4)          // 7,500,000
#define NQ_W1  (H1 * KPAD / 4)          // 327,680
#define NQ_W2  (H1 * H2 / 4)            // 1,048,576
#define NQ_WO  (CPAD * H2 / 4)          // 655,360
#define NQ_XT  (S * BATCH / 4)          // 262,144
#define NQ_TOT (NQ_EMB + NQ_W1 + NQ_W2 + NQ_WO + NQ_XT)

__global__ __launch_bounds__(256) void cvt_all(const float* __restrict__ Ein,
                                               ushort* __restrict__ Eb,
                                               const float* __restrict__ W1,
                                               ushort* __restrict__ W1p,
                                               const float* __restrict__ W2,
                                               ushort* __restrict__ W2b,
                                               const float* __restrict__ Wout,
                                               ushort* __restrict__ Woutp,
                                               const int* __restrict__ x,
                                               int* __restrict__ xT) {
  int q = blockIdx.x * 256 + threadIdx.x;
  if (q < NQ_EMB) {
    float4 v = ((const float4*)Ein)[q];
    ushort4 o;
    o.x = f2b(v.x); o.y = f2b(v.y); o.z = f2b(v.z); o.w = f2b(v.w);
    ((ushort4*)Eb)[q] = o;
    return;
  }
  q -= NQ_EMB;
  if (q < NQ_W1) {
    int row = q / 160;                 // 640/4 quads per padded row
    int k0 = (q - row * 160) * 4;
    ushort4 o; o.x = 0; o.y = 0; o.z = 0; o.w = 0;
    if (k0 < 2 * E) {
      float4 v = *(const float4*)(W1 + (size_t)row * (2 * E) + k0);
      o.x = f2b(v.x); o.y = f2b(v.y); o.z = f2b(v.z); o.w = f2b(v.w);
    }
    ((ushort4*)W1p)[q] = o;
    return;
  }
  q -= NQ_W1;
  if (q < NQ_W2) {
    float4 v = ((const float4*)W2)[q];
    ushort4 o;
    o.x = f2b(v.x); o.y = f2b(v.y); o.z = f2b(v.z); o.w = f2b(v.w);
    ((ushort4*)W2b)[q] = o;
    return;
  }
  q -= NQ_W2;
  if (q < NQ_WO) {
    int n = (q * 4) >> 11;             // row in padded [1280, 2048]
    ushort4 o; o.x = 0; o.y = 0; o.z = 0; o.w = 0;
    if (n < CLS) {
      float4 v = ((const float4*)Wout)[q];
      o.x = f2b(v.x); o.y = f2b(v.y); o.z = f2b(v.z); o.w = f2b(v.w);
    }
    ((ushort4*)Woutp)[q] = o;
    return;
  }
  q -= NQ_WO;
  if (q < NQ_XT) {
    int b = q >> 5;                    // 32 quads per sentence (128 tokens)
    int t4 = (q & 31) * 4;
    int4 o;
    o.x = x[(size_t)(t4 + 0) * BATCH + b];
    o.y = x[(size_t)(t4 + 1) * BATCH + b];
    o.z = x[(size_t)(t4 + 2) * BATCH + b];
    o.w = x[(size_t)(t4 + 3) * BATCH + b];
    ((int4*)xT)[q] = o;
  }
}

// ---------------------------------------------------------------------------
// Stage 1: embedding gather + first-token + masked mean -> feat [B, 640] bf16
// One block (128 threads = 2 waves) per sentence; emb is the bf16 copy.
// Gather is random-access-bound (~630 MB logical @ ~6.3 TB/s); at ceiling.
__global__ __launch_bounds__(128) void embed_kernel(const int* __restrict__ xT,
                                                    const ushort* __restrict__ emb,
                                                    ushort* __restrict__ feat) {
  __shared__ uint offs[S];
  __shared__ unsigned long long masks[2];
  __shared__ __align__(16) float part[76 * 4];   // wave1 partials: 75 chunks x4
  const int b = blockIdx.x;
  const int t = threadIdx.x;

  int tok = xT[b * S + t];             // coalesced
  offs[t] = (uint)tok * 600u;          // byte offset into bf16 emb table
  unsigned long long m = __ballot(tok != PADTOK);
  if ((t & 63) == 0) masks[t >> 6] = m;
  __syncthreads();

  unsigned long long m0 = masks[0], m1 = masks[1];
  int last;
  if (m1)      last = 127 - __clzll(m1);
  else if (m0) last = 63 - __clzll(m0);
  else         last = S - 1;           // all-pad: ref argmax gives last=S-1
  const int n = last + 1;
  const float inv = 1.0f / (float)n;

  const int w = t >> 6;                // wave id: wave0 even tokens, wave1 odd
  const int lane = t & 63;
  const char* base = (const char*)emb;
  const uint off0 = (uint)lane * 8u;   // chunk byte offset within row (0..511)
  const bool tail = (lane < 11);       // chunks 64..74 cover bytes 512..599
  const uint off1 = 512u + (uint)lane * 8u;

  float a0 = 0.f, a1 = 0.f, a2 = 0.f, a3 = 0.f;   // chunk `lane`
  float c0 = 0.f, c1 = 0.f, c2 = 0.f, c3 = 0.f;   // chunk 64+lane (tail lanes)

  int s = w;
  // main loop: 8 tokens per wave per iteration (16-token span)
  for (; s + 14 < n; s += 16) {
    uint o[8];
#pragma unroll
    for (int j = 0; j < 8; j++) o[j] = offs[s + 2 * j];
    ushort4 u[8];
#pragma unroll
    for (int j = 0; j < 8; j++) u[j] = *(const ushort4*)(base + (o[j] + off0));
    ushort4 v[8];
    if (tail) {
#pragma unroll
      for (int j = 0; j < 8; j++) v[j] = *(const ushort4*)(base + (o[j] + off1));
    }
#pragma unroll
    for (int j = 0; j < 8; j++) {
      a0 += b2f(u[j].x); a1 += b2f(u[j].y);
      a2 += b2f(u[j].z); a3 += b2f(u[j].w);
    }
    if (tail) {
#pragma unroll
      for (int j = 0; j < 8; j++) {
        c0 += b2f(v[j].x); c1 += b2f(v[j].y);
        c2 += b2f(v[j].z); c3 += b2f(v[j].w);
      }
    }
  }
  for (; s < n; s += 2) {
    uint o = offs[s];
    ushort4 u = *(const ushort4*)(base + (o + off0));
    a0 += b2f(u.x); a1 += b2f(u.y); a2 += b2f(u.z); a3 += b2f(u.w);
    if (tail) {
      ushort4 v = *(const ushort4*)(base + (o + off1));
      c0 += b2f(v.x); c1 += b2f(v.y); c2 += b2f(v.z); c3 += b2f(v.w);
    }
  }

  // cross-wave combine: wave1 publishes partials, wave0 reduces + stores mean
  if (w == 1) {
    float4 av; av.x = a0; av.y = a1; av.z = a2; av.w = a3;
    *(float4*)&part[lane * 4] = av;
    if (tail) {
      float4 cv; cv.x = c0; cv.y = c1; cv.z = c2; cv.w = c3;
      *(float4*)&part[(64 + lane) * 4] = cv;
    }
  }
  __syncthreads();

  ushort* fr = feat + (size_t)b * KPAD;
  if (w == 0) {
    float4 pv = *(const float4*)&part[lane * 4];
    ushort4 mo;
    mo.x = f2b((a0 + pv.x) * inv); mo.y = f2b((a1 + pv.y) * inv);
    mo.z = f2b((a2 + pv.z) * inv); mo.w = f2b((a3 + pv.w) * inv);
    *(ushort4*)(fr + E + lane * 4) = mo;           // byte 600+8*lane, aligned
    if (tail) {
      float4 qv = *(const float4*)&part[(64 + lane) * 4];
      ushort4 mo2;
      mo2.x = f2b((c0 + qv.x) * inv); mo2.y = f2b((c1 + qv.y) * inv);
      mo2.z = f2b((c2 + qv.z) * inv); mo2.w = f2b((c3 + qv.w) * inv);
      *(ushort4*)(fr + E + (64 + lane) * 4) = mo2;
    }
  }

  // first-token half: direct bf16 copy (75 threads x 8 B = 600 B)
  const uint o0 = offs[0];
  if (t < 75) {
    *(ushort4*)(fr + 4 * t) = *(const ushort4*)(base + (o0 + 8u * (uint)t));
  } else if (t < 85) {
    // zero the K padding 600..639 (10 threads x 4 elems)
    ushort4 z; z.x = 0; z.y = 0; z.z = 0; z.w = 0;
    *(ushort4*)(fr + 2 * E + 4 * (t - 75)) = z;
  }
}

// ---------------------------------------------------------------------------
// GEMM: C[M,N] = act(A[M,K] * B[N,K]^T + bias), A/B bf16, fp32 MFMA accum.
// 256x256 tile, BK=64, 512 threads (8 waves as 2M x 4N; per-wave 128x64 out
// via acc[8][4] of 16x16x32 MFMA). Deep pipeline (T1+T3+T4+T5):
//   - LDS 128 KB: 2 slots x (A 32KB + B 32KB); slot = tile parity.
//   - Half-tile = K-split: 256 rows x 32 k = 16 KB = 2 global_load_lds/thread.
//   - 4 phases per K-tile, phase (kh,mh): {ds_read 4-or-8 b128 | stage one
//     half of tile t+1 into other slot} -> [vmcnt(4) at phases 2,4] ->
//     s_barrier -> setprio(1) 16 MFMA setprio(0) -> s_barrier.
//   - vmcnt(4) derivation: at each wait exactly 2 younger halves (4 loads
//     per wave) may stay in flight; the 2 oldest halves (the ones the next
//     phase reads) drain. Never vmcnt(0) in the main loop.
//   - Stage-write safety: half staged in phase p was last ds_read in phase
//     <= p-1; each wave's reads are lgkmcnt-drained before its MFMA and the
//     end-of-phase barrier seals them block-wide before any later stage.
//   - Swizzle (both-sides, #21): stored chunk slot = c ^ ((row>>1)&3) within
//     a half's 4 chunks; applied on the global SOURCE k-chunk at stage time
//     and on the ds_read address. 16-lane frag read groups hit each bank
//     at most 2-way (free).
//   - T1 XCD swizzle: all grids have nwg%8==0 (256/256/160); remap so each
//     XCD owns nwg/8 consecutive linear tiles -> A-panels fetched once per
//     XCD L2 instead of 8x.
#define BM2 256
#define BN2 256
#define BK2 64

// stage one K-half (256 rows x 32 k) of operand P into LDS half-region dst.
// dst is the element base of the half region; dest must stay lane-linear.
__device__ __forceinline__ void stage_half(const ushort* __restrict__ P,
                                           int ld, int org, ushort* dst,
                                           int kg, int tid, int wave) {
  const int sc = tid & 3;              // stored chunk slot
  const int r0 = tid >> 2;             // row within 128-row j-block
#pragma unroll
  for (int j = 0; j < 2; ++j) {
    const int row = j * 128 + r0;
    const int c2 = sc ^ ((row >> 1) & 3);       // source k-chunk (swizzled)
    async16(P + (size_t)(org + row) * ld + kg + c2 * 8,
            (void*)(dst + j * 4096 + wave * 512));
  }
}

#define PH_READ_B(KH)                                                        \
  _Pragma("unroll") for (int nf = 0; nf < 4; ++nf) {                         \
    const int row = wc * 64 + nf * 16 + fr;                                  \
    bfrag[nf] = *(const bf16x8*)&sB[(KH) * 8192 + row * 32 +                 \
                                    ((fq ^ ((row >> 1) & 3)) * 8)];          \
  }
#define PH_READ_A(MH, KH)                                                    \
  _Pragma("unroll") for (int f = 0; f < 4; ++f) {                            \
    const int row = wr * 128 + (MH) * 64 + f * 16 + fr;                      \
    afrag[f] = *(const bf16x8*)&sA[(KH) * 8192 + row * 32 +                  \
                                   ((fq ^ ((row >> 1) & 3)) * 8)];           \
  }
#define PH_MFMA(MH)                                                          \
  __builtin_amdgcn_s_setprio(1);                                             \
  _Pragma("unroll") for (int f = 0; f < 4; ++f)                              \
    _Pragma("unroll") for (int nf = 0; nf < 4; ++nf)                         \
      acc[(MH) * 4 + f][nf] = __builtin_amdgcn_mfma_f32_16x16x32_bf16(       \
          afrag[f], bfrag[nf], acc[(MH) * 4 + f][nf], 0, 0, 0);              \
  __builtin_amdgcn_s_setprio(0);
#define BAR_SCHED()                                                          \
  __builtin_amdgcn_s_barrier();                                              \
  __builtin_amdgcn_sched_barrier(0);

template <bool RELU, bool NGUARD, bool FP32OUT>
__global__ __launch_bounds__(512, 2) void gemm_bt(const ushort* __restrict__ A,
                                                  const ushort* __restrict__ B,
                                                  const float* __restrict__ bias,
                                                  void* __restrict__ Cv,
                                                  int K, int lda, int ldb,
                                                  int ldc, int Nreal) {
  __shared__ __align__(16) ushort sm[65536];    // 128 KB: [2 slots][A|B][2 kh][256][4*8]

  const int tid = threadIdx.x;
  const int wave = tid >> 6;
  const int lane = tid & 63;

  // T1: XCD-aware bijective block swizzle (requires nwg % 8 == 0 — holds
  // for all three layers: 256 / 256 / 160 workgroups).
  const int gx = gridDim.x;
  const int nwg = gx * gridDim.y;
  const int lin = blockIdx.y * gx + blockIdx.x;
  const int wsw = (lin & 7) * (nwg >> 3) + (lin >> 3);
  const int m0 = (wsw / gx) * BM2;
  const int n0 = (wsw % gx) * BN2;

  const int wr = wave >> 2;            // 0..1 : row half of tile
  const int wc = wave & 3;             // 0..3 : 64-col slice
  const int fr = lane & 15;            // fragment row
  const int fq = lane >> 4;            // k-chunk within half (0..3)

  f32x4 acc[8][4];
#pragma unroll
  for (int i = 0; i < 8; ++i)
#pragma unroll
    for (int j = 0; j < 4; ++j)
#pragma unroll
      for (int r = 0; r < 4; ++r) acc[i][j][r] = 0.f;

  bf16x8 afrag[4], bfrag[4];
  const int NT = K / BK2;

  // prologue: stage tile0 (A-kh0, B-kh0, A-kh1, B-kh1) into slot 0
  {
    ushort* sA0 = sm;
    ushort* sB0 = sm + 16384;
    stage_half(A, lda, m0, sA0, 0, tid, wave);
    stage_half(B, ldb, n0, sB0, 0, tid, wave);
    stage_half(A, lda, m0, sA0 + 8192, 32, tid, wave);
    stage_half(B, ldb, n0, sB0 + 8192, 32, tid, wave);
    asm volatile("s_waitcnt vmcnt(4)" ::: "memory");
    BAR_SCHED();
  }

  for (int t = 0; t < NT - 1; ++t) {
    const int s = t & 1;
    ushort* sA = sm + s * 32768;
    ushort* sB = sA + 16384;
    ushort* dA = sm + (s ^ 1) * 32768;
    ushort* dB = dA + 16384;
    const int kn = (t + 1) * BK2;

    // p0: (kh0, mh0) + stage A-kh0(t+1)
    PH_READ_B(0);
    PH_READ_A(0, 0);
    stage_half(A, lda, m0, dA, kn, tid, wave);
    BAR_SCHED();
    PH_MFMA(0);
    BAR_SCHED();

    // p1: (kh0, mh1) + stage B-kh0(t+1); drain A/B-kh1 of tile t
    PH_READ_A(1, 0);
    stage_half(B, ldb, n0, dB, kn, tid, wave);
    asm volatile("s_waitcnt vmcnt(4)" ::: "memory");
    BAR_SCHED();
    PH_MFMA(1);
    BAR_SCHED();

    // p2: (kh1, mh0) + stage A-kh1(t+1)
    PH_READ_B(1);
    PH_READ_A(0, 1);
    stage_half(A, lda, m0, dA + 8192, kn + 32, tid, wave);
    BAR_SCHED();
    PH_MFMA(0);
    BAR_SCHED();

    // p3: (kh1, mh1) + stage B-kh1(t+1); drain A/B-kh0 of tile t+1
    PH_READ_A(1, 1);
    stage_half(B, ldb, n0, dB + 8192, kn + 32, tid, wave);
    asm volatile("s_waitcnt vmcnt(4)" ::: "memory");
    BAR_SCHED();
    PH_MFMA(1);
    BAR_SCHED();
  }

  // last tile: no staging; kh1 halves drained at p1 with vmcnt(0)
  {
    const int s = (NT - 1) & 1;
    ushort* sA = sm + s * 32768;
    ushort* sB = sA + 16384;

    PH_READ_B(0);
    PH_READ_A(0, 0);
    BAR_SCHED();
    PH_MFMA(0);
    BAR_SCHED();

    PH_READ_A(1, 0);
    asm volatile("s_waitcnt vmcnt(0)" ::: "memory");
    BAR_SCHED();
    PH_MFMA(1);
    BAR_SCHED();

    PH_READ_B(1);
    PH_READ_A(0, 1);
    BAR_SCHED();
    PH_MFMA(0);
    BAR_SCHED();

    PH_READ_A(1, 1);
    PH_MFMA(1);
  }

  // Epilogue. 16x16 C/D layout: col = lane&15, row = (lane>>4)*4 + reg.
  // acc[g][nf]: row block = wr*128 + (g>>2)*64 + (g&3)*16.
#pragma unroll
  for (int nf = 0; nf < 4; ++nf) {
    const int col = n0 + wc * 64 + nf * 16 + fr;
    const bool ok = (!NGUARD) || (col < Nreal);
    const float bv = ok ? bias[col] : 0.f;
#pragma unroll
    for (int g = 0; g < 8; ++g) {
      const int rbase = m0 + wr * 128 + (g >> 2) * 64 + (g & 3) * 16 + fq * 4;
#pragma unroll
      for (int rr = 0; rr < 4; ++rr) {
        const int row = rbase + rr;
        float v = acc[g][nf][rr] + bv;
        if (RELU) v = fmaxf(v, 0.f);
        if (ok) {
          if (FP32OUT) ((float*)Cv)[(size_t)row * ldc + col] = v;
          else         ((ushort*)Cv)[(size_t)row * ldc + col] = f2b(v);
        }
      }
    }
  }
}

// ---------------------------------------------------------------------------
extern "C" void kernel_launch(void* const* d_in, const int* in_sizes, int n_in,
                              void* d_out, int out_size, void* d_ws, size_t ws_size,
                              hipStream_t stream) {
  const int* x = (const int*)d_in[0];
  const float* emb = (const float*)d_in[1];
  const float* W1 = (const float*)d_in[2];
  const float* b1 = (const float*)d_in[3];
  const float* W2 = (const float*)d_in[4];
  const float* b2 = (const float*)d_in[5];
  const float* Wout = (const float*)d_in[6];
  const float* bout = (const float*)d_in[7];
  float* out = (float*)d_out;

  char* ws = (char*)d_ws;
  ushort* feat = (ushort*)ws;  ws += (size_t)BATCH * KPAD * 2;   // 10.5 MB
  ushort* h1 = (ushort*)ws;    ws += (size_t)BATCH * H1 * 2;     // 33.6 MB
  ushort* h2 = (ushort*)ws;    ws += (size_t)BATCH * H2 * 2;     // 33.6 MB
  ushort* W1p = (ushort*)ws;   ws += (size_t)H1 * KPAD * 2;      // 2.6 MB
  ushort* W2b = (ushort*)ws;   ws += (size_t)H2 * H1 * 2;        // 8.4 MB
  ushort* Woutp = (ushort*)ws; ws += (size_t)CPAD * H2 * 2;      // 5.2 MB
  ushort* Eb = (ushort*)ws;    ws += (size_t)VOCAB * E * 2;      // 60 MB
  int* xT = (int*)ws;          ws += (size_t)S * BATCH * 4;      // 4 MB

  cvt_all<<<(NQ_TOT + 255) / 256, 256, 0, stream>>>(emb, Eb, W1, W1p, W2, W2b,
                                                    Wout, Woutp, x, xT);
  embed_kernel<<<BATCH, S, 0, stream>>>(xT, Eb, feat);

  // L1: feat[8192,640] x W1p[2048,640]^T -> relu -> h1[8192,2048] bf16
  gemm_bt<true, false, false><<<dim3(H1 / BN2, BATCH / BM2), 512, 0, stream>>>(
      feat, W1p, b1, (void*)h1, KPAD, KPAD, KPAD, H1, H1);
  // L2: h1 x W2b[2048,2048]^T -> relu -> h2 bf16
  gemm_bt<true, false, false><<<dim3(H2 / BN2, BATCH / BM2), 512, 0, stream>>>(
      h1, W2b, b2, (void*)h2, H1, H1, H1, H2, H2);
  // L3: h2 x Woutp[1280,2048]^T + bias -> out[8192,1221] fp32 (guarded)
  gemm_bt<false, true, true><<<dim3(CPAD / BN2, BATCH / BM2), 512, 0, stream>>>(
      h2, Woutp, bout, (void*)out, H2, H2, H2, CLS, CLS);
}

// Round 5
// 490.936 us; speedup vs baseline: 1.0267x; 1.0033x over previous
//
#include <hip/hip_runtime.h>
#include <hip/hip_bf16.h>

// Problem constants
#define S 128
#define BATCH 8192
#define E 300
#define KPAD 640            // 2E=600 padded to multiple of 64
#define H1 2048
#define H2 2048
#define CLS 1221
#define CPAD 1280           // padded N for last GEMM
#define PADTOK 1
#define VOCAB 100000

typedef __bf16 bf16x8 __attribute__((ext_vector_type(8)));
typedef float f32x4 __attribute__((ext_vector_type(4)));

__device__ __forceinline__ float b2f(ushort u) {
  union { unsigned int i; float f; } v; v.i = ((unsigned int)u) << 16; return v.f;
}
__device__ __forceinline__ ushort f2b(float f) {
  unsigned int i = __float_as_uint(f);
  unsigned int r = (i + 0x7FFFu + ((i >> 16) & 1u)) >> 16;
  return (ushort)r;
}
__device__ __forceinline__ void async16(const void* g, void* l) {
  __builtin_amdgcn_global_load_lds(
      (__attribute__((address_space(1))) void*)(void*)(const_cast<void*>(g)),
      (__attribute__((address_space(3))) void*)l, 16, 0, 0);
}

// ---------------------------------------------------------------------------
// Fused preprocessing: emb->bf16, W1->bf16 pad, W2->bf16, Wout->bf16 pad,
// x transpose. One quad (4 elements) per thread.
#define NQ_EMB (VOCAB * E / 4)          // 7,500,000
#define NQ_W1  (H1 * KPAD / 4)          // 327,680
#define NQ_W2  (H1 * H2 / 4)            // 1,048,576
#define NQ_WO  (CPAD * H2 / 4)          // 655,360
#define NQ_XT  (S * BATCH / 4)          // 262,144
#define NQ_TOT (NQ_EMB + NQ_W1 + NQ_W2 + NQ_WO + NQ_XT)

__global__ __launch_bounds__(256) void cvt_all(const float* __restrict__ Ein,
                                               ushort* __restrict__ Eb,
                                               const float* __restrict__ W1,
                                               ushort* __restrict__ W1p,
                                               const float* __restrict__ W2,
                                               ushort* __restrict__ W2b,
                                               const float* __restrict__ Wout,
                                               ushort* __restrict__ Woutp,
                                               const int* __restrict__ x,
                                               int* __restrict__ xT) {
  int q = blockIdx.x * 256 + threadIdx.x;
  if (q < NQ_EMB) {
    float4 v = ((const float4*)Ein)[q];
    ushort4 o;
    o.x = f2b(v.x); o.y = f2b(v.y); o.z = f2b(v.z); o.w = f2b(v.w);
    ((ushort4*)Eb)[q] = o;
    return;
  }
  q -= NQ_EMB;
  if (q < NQ_W1) {
    int row = q / 160;                 // 640/4 quads per padded row
    int k0 = (q - row * 160) * 4;
    ushort4 o; o.x = 0; o.y = 0; o.z = 0; o.w = 0;
    if (k0 < 2 * E) {
      float4 v = *(const float4*)(W1 + (size_t)row * (2 * E) + k0);
      o.x = f2b(v.x); o.y = f2b(v.y); o.z = f2b(v.z); o.w = f2b(v.w);
    }
    ((ushort4*)W1p)[q] = o;
    return;
  }
  q -= NQ_W1;
  if (q < NQ_W2) {
    float4 v = ((const float4*)W2)[q];
    ushort4 o;
    o.x = f2b(v.x); o.y = f2b(v.y); o.z = f2b(v.z); o.w = f2b(v.w);
    ((ushort4*)W2b)[q] = o;
    return;
  }
  q -= NQ_W2;
  if (q < NQ_WO) {
    int n = (q * 4) >> 11;             // row in padded [1280, 2048]
    ushort4 o; o.x = 0; o.y = 0; o.z = 0; o.w = 0;
    if (n < CLS) {
      float4 v = ((const float4*)Wout)[q];
      o.x = f2b(v.x); o.y = f2b(v.y); o.z = f2b(v.z); o.w = f2b(v.w);
    }
    ((ushort4*)Woutp)[q] = o;
    return;
  }
  q -= NQ_WO;
  if (q < NQ_XT) {
    int b = q >> 5;                    // 32 quads per sentence (128 tokens)
    int t4 = (q & 31) * 4;
    int4 o;
    o.x = x[(size_t)(t4 + 0) * BATCH + b];
    o.y = x[(size_t)(t4 + 1) * BATCH + b];
    o.z = x[(size_t)(t4 + 2) * BATCH + b];
    o.w = x[(size_t)(t4 + 3) * BATCH + b];
    ((int4*)xT)[q] = o;
  }
}

// ---------------------------------------------------------------------------
// Stage 1: embedding gather + first-token + masked mean -> feat [B, 640] bf16
// One block (128 threads = 2 waves) per sentence; emb is the bf16 copy.
// Gather is random-access-bound (~630 MB logical @ ~6.3 TB/s); at ceiling.
__global__ __launch_bounds__(128) void embed_kernel(const int* __restrict__ xT,
                                                    const ushort* __restrict__ emb,
                                                    ushort* __restrict__ feat) {
  __shared__ uint offs[S];
  __shared__ unsigned long long masks[2];
  __shared__ __align__(16) float part[76 * 4];   // wave1 partials: 75 chunks x4
  const int b = blockIdx.x;
  const int t = threadIdx.x;

  int tok = xT[b * S + t];             // coalesced
  offs[t] = (uint)tok * 600u;          // byte offset into bf16 emb table
  unsigned long long m = __ballot(tok != PADTOK);
  if ((t & 63) == 0) masks[t >> 6] = m;
  __syncthreads();

  unsigned long long m0 = masks[0], m1 = masks[1];
  int last;
  if (m1)      last = 127 - __clzll(m1);
  else if (m0) last = 63 - __clzll(m0);
  else         last = S - 1;           // all-pad: ref argmax gives last=S-1
  const int n = last + 1;
  const float inv = 1.0f / (float)n;

  const int w = t >> 6;                // wave id: wave0 even tokens, wave1 odd
  const int lane = t & 63;
  const char* base = (const char*)emb;
  const uint off0 = (uint)lane * 8u;   // chunk byte offset within row (0..511)
  const bool tail = (lane < 11);       // chunks 64..74 cover bytes 512..599
  const uint off1 = 512u + (uint)lane * 8u;

  float a0 = 0.f, a1 = 0.f, a2 = 0.f, a3 = 0.f;   // chunk `lane`
  float c0 = 0.f, c1 = 0.f, c2 = 0.f, c3 = 0.f;   // chunk 64+lane (tail lanes)

  int s = w;
  // main loop: 8 tokens per wave per iteration (16-token span)
  for (; s + 14 < n; s += 16) {
    uint o[8];
#pragma unroll
    for (int j = 0; j < 8; j++) o[j] = offs[s + 2 * j];
    ushort4 u[8];
#pragma unroll
    for (int j = 0; j < 8; j++) u[j] = *(const ushort4*)(base + (o[j] + off0));
    ushort4 v[8];
    if (tail) {
#pragma unroll
      for (int j = 0; j < 8; j++) v[j] = *(const ushort4*)(base + (o[j] + off1));
    }
#pragma unroll
    for (int j = 0; j < 8; j++) {
      a0 += b2f(u[j].x); a1 += b2f(u[j].y);
      a2 += b2f(u[j].z); a3 += b2f(u[j].w);
    }
    if (tail) {
#pragma unroll
      for (int j = 0; j < 8; j++) {
        c0 += b2f(v[j].x); c1 += b2f(v[j].y);
        c2 += b2f(v[j].z); c3 += b2f(v[j].w);
      }
    }
  }
  for (; s < n; s += 2) {
    uint o = offs[s];
    ushort4 u = *(const ushort4*)(base + (o + off0));
    a0 += b2f(u.x); a1 += b2f(u.y); a2 += b2f(u.z); a3 += b2f(u.w);
    if (tail) {
      ushort4 v = *(const ushort4*)(base + (o + off1));
      c0 += b2f(v.x); c1 += b2f(v.y); c2 += b2f(v.z); c3 += b2f(v.w);
    }
  }

  // cross-wave combine: wave1 publishes partials, wave0 reduces + stores mean
  if (w == 1) {
    float4 av; av.x = a0; av.y = a1; av.z = a2; av.w = a3;
    *(float4*)&part[lane * 4] = av;
    if (tail) {
      float4 cv; cv.x = c0; cv.y = c1; cv.z = c2; cv.w = c3;
      *(float4*)&part[(64 + lane) * 4] = cv;
    }
  }
  __syncthreads();

  ushort* fr = feat + (size_t)b * KPAD;
  if (w == 0) {
    float4 pv = *(const float4*)&part[lane * 4];
    ushort4 mo;
    mo.x = f2b((a0 + pv.x) * inv); mo.y = f2b((a1 + pv.y) * inv);
    mo.z = f2b((a2 + pv.z) * inv); mo.w = f2b((a3 + pv.w) * inv);
    *(ushort4*)(fr + E + lane * 4) = mo;           // byte 600+8*lane, aligned
    if (tail) {
      float4 qv = *(const float4*)&part[(64 + lane) * 4];
      ushort4 mo2;
      mo2.x = f2b((c0 + qv.x) * inv); mo2.y = f2b((c1 + qv.y) * inv);
      mo2.z = f2b((c2 + qv.z) * inv); mo2.w = f2b((c3 + qv.w) * inv);
      *(ushort4*)(fr + E + (64 + lane) * 4) = mo2;
    }
  }

  // first-token half: direct bf16 copy (75 threads x 8 B = 600 B)
  const uint o0 = offs[0];
  if (t < 75) {
    *(ushort4*)(fr + 4 * t) = *(const ushort4*)(base + (o0 + 8u * (uint)t));
  } else if (t < 85) {
    // zero the K padding 600..639 (10 threads x 4 elems)
    ushort4 z; z.x = 0; z.y = 0; z.z = 0; z.w = 0;
    *(ushort4*)(fr + 2 * E + 4 * (t - 75)) = z;
  }
}

// ---------------------------------------------------------------------------
// GEMM: C[M,N] = act(A[M,K] * B[N,K]^T + bias), A/B bf16, fp32 MFMA accum.
// 256x256 tile, BK=32, 512 threads (8 waves as 2M x 4N; per-wave 128x64 out
// via acc[8][4] of 16x16x32 MFMA). DEEP pipeline (prefetch distance 3):
//   - LDS 128 KB = 4 slots x (A 16KB + B 16KB); slot = t & 3.
//   - Tile t's loads issued during tile t-3 (A in p0, B in p1); required
//     landed at tile t-1's p1 vmcnt(8) -> ~4.5 phases (~700+ cy) of slack,
//     vs the previous distance-1 design whose vmcnt drained the very halves
//     needed next phase (~300 cy slack -> stalled; R4 was neutral).
//   - Steady-state ledger: after tile t p1 vmcnt(8), in flight = exactly
//     {A,B(t+2), A,B(t+3)} (8 loads). Never drains below 8 in main loop.
//   - Peeled tail: NT-3 -> vmcnt(4), NT-2 -> vmcnt(0), NT-1 -> none.
//   - Slot-reuse race: slot t%4 rewritten at tile t+1 p0, strictly after
//     tile t's ds_reads sealed by its p1 end barrier. 2 phases/tile,
//     16 MFMA per barrier-pair, setprio(1) around MFMA (T5).
//   - Swizzle (both-sides, #21): stored chunk slot = c ^ ((row>>1)&3);
//     applied on the global SOURCE chunk at stage time and on the ds_read
//     address. Quarter-wave read groups tile all 32 banks exactly 2-way.
//   - T1 XCD swizzle: all grids have nwg%8==0 (256/256/160).
#define BM2 256
#define BN2 256
#define BK2 32

// stage one 256x32 slab of operand P into LDS region dst (lane-linear dest).
__device__ __forceinline__ void stage32(const ushort* __restrict__ P,
                                        int ld, int org, ushort* dst,
                                        int kg, int tid, int wave) {
  const int sc = tid & 3;              // stored chunk slot
  const int r0 = tid >> 2;             // row within 128-row j-block
#pragma unroll
  for (int j = 0; j < 2; ++j) {
    const int row = j * 128 + r0;
    const int c2 = sc ^ ((row >> 1) & 3);       // source k-chunk (swizzled)
    async16(P + (size_t)(org + row) * ld + kg + c2 * 8,
            (void*)(dst + j * 4096 + wave * 512));
  }
}

#define PH_READ_B()                                                          \
  _Pragma("unroll") for (int nf = 0; nf < 4; ++nf) {                         \
    const int row = wc * 64 + nf * 16 + fr;                                  \
    bfrag[nf] = *(const bf16x8*)&sB[row * 32 +                               \
                                    ((fq ^ ((row >> 1) & 3)) * 8)];          \
  }
#define PH_READ_A(MH)                                                        \
  _Pragma("unroll") for (int f = 0; f < 4; ++f) {                            \
    const int row = wr * 128 + (MH) * 64 + f * 16 + fr;                      \
    afrag[f] = *(const bf16x8*)&sA[row * 32 +                                \
                                   ((fq ^ ((row >> 1) & 3)) * 8)];           \
  }
#define PH_MFMA(MH)                                                          \
  __builtin_amdgcn_s_setprio(1);                                             \
  _Pragma("unroll") for (int f = 0; f < 4; ++f)                              \
    _Pragma("unroll") for (int nf = 0; nf < 4; ++nf)                         \
      acc[(MH) * 4 + f][nf] = __builtin_amdgcn_mfma_f32_16x16x32_bf16(       \
          afrag[f], bfrag[nf], acc[(MH) * 4 + f][nf], 0, 0, 0);              \
  __builtin_amdgcn_s_setprio(0);
#define BAR_SCHED()                                                          \
  __builtin_amdgcn_s_barrier();                                              \
  __builtin_amdgcn_sched_barrier(0);

template <bool RELU, bool NGUARD, bool FP32OUT>
__global__ __launch_bounds__(512, 2) void gemm_bt(const ushort* __restrict__ A,
                                                  const ushort* __restrict__ B,
                                                  const float* __restrict__ bias,
                                                  void* __restrict__ Cv,
                                                  int K, int lda, int ldb,
                                                  int ldc, int Nreal) {
  __shared__ __align__(16) ushort sm[65536];    // 128 KB: 4 slots x 32 KB

  const int tid = threadIdx.x;
  const int wave = tid >> 6;
  const int lane = tid & 63;

  // T1: XCD-aware bijective block swizzle (nwg % 8 == 0 for all layers).
  const int gx = gridDim.x;
  const int nwg = gx * gridDim.y;
  const int lin = blockIdx.y * gx + blockIdx.x;
  const int wsw = (lin & 7) * (nwg >> 3) + (lin >> 3);
  const int m0 = (wsw / gx) * BM2;
  const int n0 = (wsw % gx) * BN2;

  const int wr = wave >> 2;            // 0..1 : row half of tile
  const int wc = wave & 3;             // 0..3 : 64-col slice
  const int fr = lane & 15;            // fragment row
  const int fq = lane >> 4;            // k-chunk within slab (0..3)

  f32x4 acc[8][4];
#pragma unroll
  for (int i = 0; i < 8; ++i)
#pragma unroll
    for (int j = 0; j < 4; ++j)
#pragma unroll
      for (int r = 0; r < 4; ++r) acc[i][j][r] = 0.f;

  bf16x8 afrag[4], bfrag[4];
  const int NT = K / BK2;              // >= 4 for all layers (20 / 64 / 64)

  // prologue: stage tiles 0,1,2 (A,B interleaved); 12 loads in flight.
  {
    stage32(A, lda, m0, sm,                 0, tid, wave);
    stage32(B, ldb, n0, sm + 8192,          0, tid, wave);
    stage32(A, lda, m0, sm + 16384,        32, tid, wave);
    stage32(B, ldb, n0, sm + 16384 + 8192, 32, tid, wave);
    stage32(A, lda, m0, sm + 32768,        64, tid, wave);
    stage32(B, ldb, n0, sm + 32768 + 8192, 64, tid, wave);
    asm volatile("s_waitcnt vmcnt(8)" ::: "memory");   // drains A0,B0
    BAR_SCHED();
  }

  // main loop: tiles 0 .. NT-4, full staging of t+3, steady vmcnt(8)
  for (int t = 0; t <= NT - 4; ++t) {
    const ushort* sA = sm + (t & 3) * 16384;
    const ushort* sB = sA + 8192;
    ushort* dst = sm + ((t + 3) & 3) * 16384;
    const int kn = (t + 3) * BK2;

    // p0: read B + A(mh0) of tile t; stage A(t+3)
    PH_READ_B();
    PH_READ_A(0);
    stage32(A, lda, m0, dst, kn, tid, wave);
    BAR_SCHED();
    PH_MFMA(0);
    BAR_SCHED();

    // p1: read A(mh1); stage B(t+3); drain A,B(t+1)
    PH_READ_A(1);
    stage32(B, ldb, n0, dst + 8192, kn, tid, wave);
    asm volatile("s_waitcnt vmcnt(8)" ::: "memory");
    BAR_SCHED();
    PH_MFMA(1);
    BAR_SCHED();
  }

  // tail tile NT-3: no staging; drain A,B(NT-2) with vmcnt(4)
  {
    const ushort* sA = sm + ((NT - 3) & 3) * 16384;
    const ushort* sB = sA + 8192;
    PH_READ_B();
    PH_READ_A(0);
    BAR_SCHED();
    PH_MFMA(0);
    BAR_SCHED();
    PH_READ_A(1);
    asm volatile("s_waitcnt vmcnt(4)" ::: "memory");
    BAR_SCHED();
    PH_MFMA(1);
    BAR_SCHED();
  }
  // tail tile NT-2: drain everything (A,B(NT-1)) with vmcnt(0)
  {
    const ushort* sA = sm + ((NT - 2) & 3) * 16384;
    const ushort* sB = sA + 8192;
    PH_READ_B();
    PH_READ_A(0);
    BAR_SCHED();
    PH_MFMA(0);
    BAR_SCHED();
    PH_READ_A(1);
    asm volatile("s_waitcnt vmcnt(0)" ::: "memory");
    BAR_SCHED();
    PH_MFMA(1);
    BAR_SCHED();
  }
  // tail tile NT-1: all loads landed; no vm waits
  {
    const ushort* sA = sm + ((NT - 1) & 3) * 16384;
    const ushort* sB = sA + 8192;
    PH_READ_B();
    PH_READ_A(0);
    BAR_SCHED();
    PH_MFMA(0);
    BAR_SCHED();
    PH_READ_A(1);
    PH_MFMA(1);
  }

  // Epilogue. 16x16 C/D layout: col = lane&15, row = (lane>>4)*4 + reg.
  // acc[g][nf]: row block = wr*128 + (g>>2)*64 + (g&3)*16.
#pragma unroll
  for (int nf = 0; nf < 4; ++nf) {
    const int col = n0 + wc * 64 + nf * 16 + fr;
    const bool ok = (!NGUARD) || (col < Nreal);
    const float bv = ok ? bias[col] : 0.f;
#pragma unroll
    for (int g = 0; g < 8; ++g) {
      const int rbase = m0 + wr * 128 + (g >> 2) * 64 + (g & 3) * 16 + fq * 4;
#pragma unroll
      for (int rr = 0; rr < 4; ++rr) {
        const int row = rbase + rr;
        float v = acc[g][nf][rr] + bv;
        if (RELU) v = fmaxf(v, 0.f);
        if (ok) {
          if (FP32OUT) ((float*)Cv)[(size_t)row * ldc + col] = v;
          else         ((ushort*)Cv)[(size_t)row * ldc + col] = f2b(v);
        }
      }
    }
  }
}

// ---------------------------------------------------------------------------
extern "C" void kernel_launch(void* const* d_in, const int* in_sizes, int n_in,
                              void* d_out, int out_size, void* d_ws, size_t ws_size,
                              hipStream_t stream) {
  const int* x = (const int*)d_in[0];
  const float* emb = (const float*)d_in[1];
  const float* W1 = (const float*)d_in[2];
  const float* b1 = (const float*)d_in[3];
  const float* W2 = (const float*)d_in[4];
  const float* b2 = (const float*)d_in[5];
  const float* Wout = (const float*)d_in[6];
  const float* bout = (const float*)d_in[7];
  float* out = (float*)d_out;

  char* ws = (char*)d_ws;
  ushort* feat = (ushort*)ws;  ws += (size_t)BATCH * KPAD * 2;   // 10.5 MB
  ushort* h1 = (ushort*)ws;    ws += (size_t)BATCH * H1 * 2;     // 33.6 MB
  ushort* h2 = (ushort*)ws;    ws += (size_t)BATCH * H2 * 2;     // 33.6 MB
  ushort* W1p = (ushort*)ws;   ws += (size_t)H1 * KPAD * 2;      // 2.6 MB
  ushort* W2b = (ushort*)ws;   ws += (size_t)H2 * H1 * 2;        // 8.4 MB
  ushort* Woutp = (ushort*)ws; ws += (size_t)CPAD * H2 * 2;      // 5.2 MB
  ushort* Eb = (ushort*)ws;    ws += (size_t)VOCAB * E * 2;      // 60 MB
  int* xT = (int*)ws;          ws += (size_t)S * BATCH * 4;      // 4 MB

  cvt_all<<<(NQ_TOT + 255) / 256, 256, 0, stream>>>(emb, Eb, W1, W1p, W2, W2b,
                                                    Wout, Woutp, x, xT);
  embed_kernel<<<BATCH, S, 0, stream>>>(xT, Eb, feat);

  // L1: feat[8192,640] x W1p[2048,640]^T -> relu -> h1[8192,2048] bf16
  gemm_bt<true, false, false><<<dim3(H1 / BN2, BATCH / BM2), 512, 0, stream>>>(
      feat, W1p, b1, (void*)h1, KPAD, KPAD, KPAD, H1, H1);
  // L2: h1 x W2b[2048,2048]^T -> relu -> h2 bf16
  gemm_bt<true, false, false><<<dim3(H2 / BN2, BATCH / BM2), 512, 0, stream>>>(
      h1, W2b, b2, (void*)h2, H1, H1, H1, H2, H2);
  // L3: h2 x Woutp[1280,2048]^T + bias -> out[8192,1221] fp32 (guarded)
  gemm_bt<false, true, true><<<dim3(CPAD / BN2, BATCH / BM2), 512, 0, stream>>>(
      h2, Woutp, bout, (void*)out, H2, H2, H2, CLS, CLS);
}

// Round 6
// 488.595 us; speedup vs baseline: 1.0316x; 1.0048x over previous
//
#include <hip/hip_runtime.h>
#include <hip/hip_bf16.h>

// Problem constants
#define S 128
#define BATCH 8192
#define E 300
#define KPAD 640            // 2E=600 padded to multiple of 64
#define H1 2048
#define H2 2048
#define CLS 1221
#define CPAD 1280           // padded N for last GEMM
#define PADTOK 1
#define VOCAB 100000

typedef __bf16 bf16x8 __attribute__((ext_vector_type(8)));
typedef float f32x4 __attribute__((ext_vector_type(4)));

__device__ __forceinline__ float b2f(ushort u) {
  union { unsigned int i; float f; } v; v.i = ((unsigned int)u) << 16; return v.f;
}
__device__ __forceinline__ ushort f2b(float f) {
  unsigned int i = __float_as_uint(f);
  unsigned int r = (i + 0x7FFFu + ((i >> 16) & 1u)) >> 16;
  return (ushort)r;
}
__device__ __forceinline__ void async16(const void* g, void* l) {
  __builtin_amdgcn_global_load_lds(
      (__attribute__((address_space(1))) void*)(void*)(const_cast<void*>(g)),
      (__attribute__((address_space(3))) void*)l, 16, 0, 0);
}

// ---------------------------------------------------------------------------
// Fused preprocessing: emb->bf16, W1->bf16 pad, W2->bf16, Wout->bf16 pad,
// x transpose. One quad (4 elements) per thread.
#define NQ_EMB (VOCAB * E / 4)          // 7,500,000
#define NQ_W1  (H1 * KPAD / 4)          // 327,680
#define NQ_W2  (H1 * H2 / 4)            // 1,048,576
#define NQ_WO  (CPAD * H2 / 4)          // 655,360
#define NQ_XT  (S * BATCH / 4)          // 262,144
#define NQ_TOT (NQ_EMB + NQ_W1 + NQ_W2 + NQ_WO + NQ_XT)

__global__ __launch_bounds__(256) void cvt_all(const float* __restrict__ Ein,
                                               ushort* __restrict__ Eb,
                                               const float* __restrict__ W1,
                                               ushort* __restrict__ W1p,
                                               const float* __restrict__ W2,
                                               ushort* __restrict__ W2b,
                                               const float* __restrict__ Wout,
                                               ushort* __restrict__ Woutp,
                                               const int* __restrict__ x,
                                               int* __restrict__ xT) {
  int q = blockIdx.x * 256 + threadIdx.x;
  if (q < NQ_EMB) {
    float4 v = ((const float4*)Ein)[q];
    ushort4 o;
    o.x = f2b(v.x); o.y = f2b(v.y); o.z = f2b(v.z); o.w = f2b(v.w);
    ((ushort4*)Eb)[q] = o;
    return;
  }
  q -= NQ_EMB;
  if (q < NQ_W1) {
    int row = q / 160;                 // 640/4 quads per padded row
    int k0 = (q - row * 160) * 4;
    ushort4 o; o.x = 0; o.y = 0; o.z = 0; o.w = 0;
    if (k0 < 2 * E) {
      float4 v = *(const float4*)(W1 + (size_t)row * (2 * E) + k0);
      o.x = f2b(v.x); o.y = f2b(v.y); o.z = f2b(v.z); o.w = f2b(v.w);
    }
    ((ushort4*)W1p)[q] = o;
    return;
  }
  q -= NQ_W1;
  if (q < NQ_W2) {
    float4 v = ((const float4*)W2)[q];
    ushort4 o;
    o.x = f2b(v.x); o.y = f2b(v.y); o.z = f2b(v.z); o.w = f2b(v.w);
    ((ushort4*)W2b)[q] = o;
    return;
  }
  q -= NQ_W2;
  if (q < NQ_WO) {
    int n = (q * 4) >> 11;             // row in padded [1280, 2048]
    ushort4 o; o.x = 0; o.y = 0; o.z = 0; o.w = 0;
    if (n < CLS) {
      float4 v = ((const float4*)Wout)[q];
      o.x = f2b(v.x); o.y = f2b(v.y); o.z = f2b(v.z); o.w = f2b(v.w);
    }
    ((ushort4*)Woutp)[q] = o;
    return;
  }
  q -= NQ_WO;
  if (q < NQ_XT) {
    int b = q >> 5;                    // 32 quads per sentence (128 tokens)
    int t4 = (q & 31) * 4;
    int4 o;
    o.x = x[(size_t)(t4 + 0) * BATCH + b];
    o.y = x[(size_t)(t4 + 1) * BATCH + b];
    o.z = x[(size_t)(t4 + 2) * BATCH + b];
    o.w = x[(size_t)(t4 + 3) * BATCH + b];
    ((int4*)xT)[q] = o;
  }
}

// ---------------------------------------------------------------------------
// Stage 1: embedding gather + first-token + masked mean -> feat [B, 640] bf16
// One block (128 threads = 2 waves) per sentence; emb is the bf16 copy.
// Gather is random-access-bound (~630 MB logical @ ~6.3 TB/s); at ceiling.
__global__ __launch_bounds__(128) void embed_kernel(const int* __restrict__ xT,
                                                    const ushort* __restrict__ emb,
                                                    ushort* __restrict__ feat) {
  __shared__ uint offs[S];
  __shared__ unsigned long long masks[2];
  __shared__ __align__(16) float part[76 * 4];   // wave1 partials: 75 chunks x4
  const int b = blockIdx.x;
  const int t = threadIdx.x;

  int tok = xT[b * S + t];             // coalesced
  offs[t] = (uint)tok * 600u;          // byte offset into bf16 emb table
  unsigned long long m = __ballot(tok != PADTOK);
  if ((t & 63) == 0) masks[t >> 6] = m;
  __syncthreads();

  unsigned long long m0 = masks[0], m1 = masks[1];
  int last;
  if (m1)      last = 127 - __clzll(m1);
  else if (m0) last = 63 - __clzll(m0);
  else         last = S - 1;           // all-pad: ref argmax gives last=S-1
  const int n = last + 1;
  const float inv = 1.0f / (float)n;

  const int w = t >> 6;                // wave id: wave0 even tokens, wave1 odd
  const int lane = t & 63;
  const char* base = (const char*)emb;
  const uint off0 = (uint)lane * 8u;   // chunk byte offset within row (0..511)
  const bool tail = (lane < 11);       // chunks 64..74 cover bytes 512..599
  const uint off1 = 512u + (uint)lane * 8u;

  float a0 = 0.f, a1 = 0.f, a2 = 0.f, a3 = 0.f;   // chunk `lane`
  float c0 = 0.f, c1 = 0.f, c2 = 0.f, c3 = 0.f;   // chunk 64+lane (tail lanes)

  int s = w;
  // main loop: 8 tokens per wave per iteration (16-token span)
  for (; s + 14 < n; s += 16) {
    uint o[8];
#pragma unroll
    for (int j = 0; j < 8; j++) o[j] = offs[s + 2 * j];
    ushort4 u[8];
#pragma unroll
    for (int j = 0; j < 8; j++) u[j] = *(const ushort4*)(base + (o[j] + off0));
    ushort4 v[8];
    if (tail) {
#pragma unroll
      for (int j = 0; j < 8; j++) v[j] = *(const ushort4*)(base + (o[j] + off1));
    }
#pragma unroll
    for (int j = 0; j < 8; j++) {
      a0 += b2f(u[j].x); a1 += b2f(u[j].y);
      a2 += b2f(u[j].z); a3 += b2f(u[j].w);
    }
    if (tail) {
#pragma unroll
      for (int j = 0; j < 8; j++) {
        c0 += b2f(v[j].x); c1 += b2f(v[j].y);
        c2 += b2f(v[j].z); c3 += b2f(v[j].w);
      }
    }
  }
  for (; s < n; s += 2) {
    uint o = offs[s];
    ushort4 u = *(const ushort4*)(base + (o + off0));
    a0 += b2f(u.x); a1 += b2f(u.y); a2 += b2f(u.z); a3 += b2f(u.w);
    if (tail) {
      ushort4 v = *(const ushort4*)(base + (o + off1));
      c0 += b2f(v.x); c1 += b2f(v.y); c2 += b2f(v.z); c3 += b2f(v.w);
    }
  }

  // cross-wave combine: wave1 publishes partials, wave0 reduces + stores mean
  if (w == 1) {
    float4 av; av.x = a0; av.y = a1; av.z = a2; av.w = a3;
    *(float4*)&part[lane * 4] = av;
    if (tail) {
      float4 cv; cv.x = c0; cv.y = c1; cv.z = c2; cv.w = c3;
      *(float4*)&part[(64 + lane) * 4] = cv;
    }
  }
  __syncthreads();

  ushort* fr = feat + (size_t)b * KPAD;
  if (w == 0) {
    float4 pv = *(const float4*)&part[lane * 4];
    ushort4 mo;
    mo.x = f2b((a0 + pv.x) * inv); mo.y = f2b((a1 + pv.y) * inv);
    mo.z = f2b((a2 + pv.z) * inv); mo.w = f2b((a3 + pv.w) * inv);
    *(ushort4*)(fr + E + lane * 4) = mo;           // byte 600+8*lane, aligned
    if (tail) {
      float4 qv = *(const float4*)&part[(64 + lane) * 4];
      ushort4 mo2;
      mo2.x = f2b((c0 + qv.x) * inv); mo2.y = f2b((c1 + qv.y) * inv);
      mo2.z = f2b((c2 + qv.z) * inv); mo2.w = f2b((c3 + qv.w) * inv);
      *(ushort4*)(fr + E + (64 + lane) * 4) = mo2;
    }
  }

  // first-token half: direct bf16 copy (75 threads x 8 B = 600 B)
  const uint o0 = offs[0];
  if (t < 75) {
    *(ushort4*)(fr + 4 * t) = *(const ushort4*)(base + (o0 + 8u * (uint)t));
  } else if (t < 85) {
    // zero the K padding 600..639 (10 threads x 4 elems)
    ushort4 z; z.x = 0; z.y = 0; z.z = 0; z.w = 0;
    *(ushort4*)(fr + 2 * E + 4 * (t - 75)) = z;
  }
}

// ---------------------------------------------------------------------------
// GEMM: C[M,N] = act(A[M,K] * B[N,K]^T + bias), A/B bf16, fp32 MFMA accum.
// 256x256 tile, BK=32, 512 threads (8 waves as 2M x 4N; per-wave 128x64 out
// via acc[8][4] of 16x16x32 MFMA). Deep pipeline + REGISTER PREFETCH:
//   - LDS 128 KB = 4 slots x (A 16KB + B 16KB); slot = t & 3; staging
//     distance 3 (tile t+3 staged during tile t), counted vmcnt(8), never 0
//     in steady state. (Identical ledger to the R5 kernel, verified passing.)
//   - NEW (the m201 mechanism R4/R5 missed): ds_reads are issued ONE MFMA
//     CLUSTER AHEAD into alternating register sets, so LDS latency lands
//     under the 16-MFMA clusters instead of serializing before them:
//       READ_A1(t) ; M0(t)            <- A1 lands under M0, lgkmcnt(4)
//       bar ; stage(t+3) ; vm(8) ; bar
//       READ_B/A0(t+1) ; M1(t)        <- next tile's 8 reads land under M1
//     Counted lgkm waits are compiler-emitted (compiler-visible ds reads).
//     2 barriers/tile; waves drift between M1/M0 -> role-split for setprio.
//   - Static regset alternation by tile parity (no runtime-indexed arrays).
//   - Swizzle (both-sides): stored chunk slot = c ^ ((row>>1)&3) applied on
//     the global SOURCE chunk at stage time and on the ds_read address;
//     16-lane frag read groups tile all 32 banks 2-way (free).
//   - T1 XCD swizzle: all grids have nwg%8==0 (256/256/160).
//   - NT = K/32 must be even and >= 4 (holds: 20 / 64 / 64).
#define BM2 256
#define BN2 256
#define BK2 32

// stage one 256x32 slab of operand P into LDS region dst (lane-linear dest).
__device__ __forceinline__ void stage32(const ushort* __restrict__ P,
                                        int ld, int org, ushort* dst,
                                        int kg, int tid, int wave) {
  const int sc = tid & 3;              // stored chunk slot
  const int r0 = tid >> 2;             // row within 128-row j-block
#pragma unroll
  for (int j = 0; j < 2; ++j) {
    const int row = j * 128 + r0;
    const int c2 = sc ^ ((row >> 1) & 3);       // source k-chunk (swizzled)
    async16(P + (size_t)(org + row) * ld + kg + c2 * 8,
            (void*)(dst + j * 4096 + wave * 512));
  }
}

#define RD_B(REG, SBASE)                                                     \
  _Pragma("unroll") for (int nf = 0; nf < 4; ++nf) {                         \
    const int row = wc * 64 + nf * 16 + fr;                                  \
    REG[nf] = *(const bf16x8*)&(SBASE)[row * 32 +                            \
                                       ((fq ^ ((row >> 1) & 3)) * 8)];       \
  }
#define RD_A(REG, SBASE, MH)                                                 \
  _Pragma("unroll") for (int f = 0; f < 4; ++f) {                            \
    const int row = wr * 128 + (MH) * 64 + f * 16 + fr;                      \
    REG[f] = *(const bf16x8*)&(SBASE)[row * 32 +                             \
                                      ((fq ^ ((row >> 1) & 3)) * 8)];        \
  }
#define MF(MH, RB, RA)                                                       \
  __builtin_amdgcn_s_setprio(1);                                             \
  _Pragma("unroll") for (int f = 0; f < 4; ++f)                              \
    _Pragma("unroll") for (int nf = 0; nf < 4; ++nf)                         \
      acc[(MH) * 4 + f][nf] = __builtin_amdgcn_mfma_f32_16x16x32_bf16(       \
          RA[f], RB[nf], acc[(MH) * 4 + f][nf], 0, 0, 0);                    \
  __builtin_amdgcn_s_setprio(0);
#define SB0() __builtin_amdgcn_sched_barrier(0)
#define BARS()                                                               \
  __builtin_amdgcn_s_barrier();                                              \
  __builtin_amdgcn_sched_barrier(0);

// steady tile body: reads for t+1 prefetched under t's MFMA clusters.
#define STEADY_BODY(T, RB, RA0, RBN, RA0N)                                   \
  {                                                                          \
    const ushort* sA_c = sm + ((T) & 3) * 16384;                             \
    RD_A(ra1, sA_c, 1);                                                      \
    SB0();                                                                   \
    MF(0, RB, RA0);                                                          \
    BARS();                                                                  \
    {                                                                        \
      ushort* dstS = sm + (((T) + 3) & 3) * 16384;                           \
      stage32(A, lda, m0, dstS, ((T) + 3) * BK2, tid, wave);                 \
      stage32(B, ldb, n0, dstS + 8192, ((T) + 3) * BK2, tid, wave);          \
    }                                                                        \
    asm volatile("s_waitcnt vmcnt(8)" ::: "memory");                         \
    BARS();                                                                  \
    {                                                                        \
      const ushort* sA_n = sm + (((T) + 1) & 3) * 16384;                     \
      RD_B(RBN, sA_n + 8192);                                                \
      RD_A(RA0N, sA_n, 0);                                                   \
    }                                                                        \
    SB0();                                                                   \
    MF(1, RB, ra1);                                                          \
  }

template <bool RELU, bool NGUARD, bool FP32OUT>
__global__ __launch_bounds__(512, 2) void gemm_bt(const ushort* __restrict__ A,
                                                  const ushort* __restrict__ B,
                                                  const float* __restrict__ bias,
                                                  void* __restrict__ Cv,
                                                  int K, int lda, int ldb,
                                                  int ldc, int Nreal) {
  __shared__ __align__(16) ushort sm[65536];    // 128 KB: 4 slots x 32 KB

  const int tid = threadIdx.x;
  const int wave = tid >> 6;
  const int lane = tid & 63;

  // T1: XCD-aware bijective block swizzle (nwg % 8 == 0 for all layers).
  const int gx = gridDim.x;
  const int nwg = gx * gridDim.y;
  const int lin = blockIdx.y * gx + blockIdx.x;
  const int wsw = (lin & 7) * (nwg >> 3) + (lin >> 3);
  const int m0 = (wsw / gx) * BM2;
  const int n0 = (wsw % gx) * BN2;

  const int wr = wave >> 2;            // 0..1 : row half of tile
  const int wc = wave & 3;             // 0..3 : 64-col slice
  const int fr = lane & 15;            // fragment row
  const int fq = lane >> 4;            // k-chunk within slab (0..3)

  f32x4 acc[8][4];
#pragma unroll
  for (int i = 0; i < 8; ++i)
#pragma unroll
    for (int j = 0; j < 4; ++j)
#pragma unroll
      for (int r = 0; r < 4; ++r) acc[i][j][r] = 0.f;

  bf16x8 rbE[4], ra0E[4], rbO[4], ra0O[4], ra1[4];
  const int NT = K / BK2;              // even, >= 4 (20 / 64 / 64)

  // prologue: stage tiles 0,1,2 (12 loads); drain tile0; read its B/A0.
  {
    stage32(A, lda, m0, sm,                 0, tid, wave);
    stage32(B, ldb, n0, sm + 8192,          0, tid, wave);
    stage32(A, lda, m0, sm + 16384,        32, tid, wave);
    stage32(B, ldb, n0, sm + 16384 + 8192, 32, tid, wave);
    stage32(A, lda, m0, sm + 32768,        64, tid, wave);
    stage32(B, ldb, n0, sm + 32768 + 8192, 64, tid, wave);
    asm volatile("s_waitcnt vmcnt(8)" ::: "memory");   // tile0 landed
    BARS();
    RD_B(rbE, sm + 8192);
    RD_A(ra0E, sm, 0);
  }

  // steady: tiles 0 .. NT-4 (odd count since NT even); unroll by 2 + single.
  int t = 0;
  for (; t + 1 <= NT - 4; t += 2) {
    STEADY_BODY(t,     rbE, ra0E, rbO, ra0O);
    STEADY_BODY(t + 1, rbO, ra0O, rbE, ra0E);
  }
  STEADY_BODY(t, rbE, ra0E, rbO, ra0O);   // t == NT-4 (even)

  // tail tile NT-3 (odd parity): no staging; vm(4) drains tile NT-2.
  {
    const ushort* sA_c = sm + ((NT - 3) & 3) * 16384;
    RD_A(ra1, sA_c, 1);
    SB0();
    MF(0, rbO, ra0O);
    BARS();
    asm volatile("s_waitcnt vmcnt(4)" ::: "memory");
    BARS();
    const ushort* sA_n = sm + ((NT - 2) & 3) * 16384;
    RD_B(rbE, sA_n + 8192);
    RD_A(ra0E, sA_n, 0);
    SB0();
    MF(1, rbO, ra1);
  }
  // tail tile NT-2 (even parity): vm(0) drains tile NT-1.
  {
    const ushort* sA_c = sm + ((NT - 2) & 3) * 16384;
    RD_A(ra1, sA_c, 1);
    SB0();
    MF(0, rbE, ra0E);
    BARS();
    asm volatile("s_waitcnt vmcnt(0)" ::: "memory");
    BARS();
    const ushort* sA_n = sm + ((NT - 1) & 3) * 16384;
    RD_B(rbO, sA_n + 8192);
    RD_A(ra0O, sA_n, 0);
    SB0();
    MF(1, rbE, ra1);
  }
  // tail tile NT-1 (odd parity): final two clusters.
  {
    const ushort* sA_c = sm + ((NT - 1) & 3) * 16384;
    RD_A(ra1, sA_c, 1);
    SB0();
    MF(0, rbO, ra0O);
    MF(1, rbO, ra1);
  }

  // Epilogue. 16x16 C/D layout: col = lane&15, row = (lane>>4)*4 + reg.
  // acc[g][nf]: row block = wr*128 + (g>>2)*64 + (g&3)*16.
#pragma unroll
  for (int nf = 0; nf < 4; ++nf) {
    const int col = n0 + wc * 64 + nf * 16 + fr;
    const bool ok = (!NGUARD) || (col < Nreal);
    const float bv = ok ? bias[col] : 0.f;
#pragma unroll
    for (int g = 0; g < 8; ++g) {
      const int rbase = m0 + wr * 128 + (g >> 2) * 64 + (g & 3) * 16 + fq * 4;
#pragma unroll
      for (int rr = 0; rr < 4; ++rr) {
        const int row = rbase + rr;
        float v = acc[g][nf][rr] + bv;
        if (RELU) v = fmaxf(v, 0.f);
        if (ok) {
          if (FP32OUT) ((float*)Cv)[(size_t)row * ldc + col] = v;
          else         ((ushort*)Cv)[(size_t)row * ldc + col] = f2b(v);
        }
      }
    }
  }
}

// ---------------------------------------------------------------------------
extern "C" void kernel_launch(void* const* d_in, const int* in_sizes, int n_in,
                              void* d_out, int out_size, void* d_ws, size_t ws_size,
                              hipStream_t stream) {
  const int* x = (const int*)d_in[0];
  const float* emb = (const float*)d_in[1];
  const float* W1 = (const float*)d_in[2];
  const float* b1 = (const float*)d_in[3];
  const float* W2 = (const float*)d_in[4];
  const float* b2 = (const float*)d_in[5];
  const float* Wout = (const float*)d_in[6];
  const float* bout = (const float*)d_in[7];
  float* out = (float*)d_out;

  char* ws = (char*)d_ws;
  ushort* feat = (ushort*)ws;  ws += (size_t)BATCH * KPAD * 2;   // 10.5 MB
  ushort* h1 = (ushort*)ws;    ws += (size_t)BATCH * H1 * 2;     // 33.6 MB
  ushort* h2 = (ushort*)ws;    ws += (size_t)BATCH * H2 * 2;     // 33.6 MB
  ushort* W1p = (ushort*)ws;   ws += (size_t)H1 * KPAD * 2;      // 2.6 MB
  ushort* W2b = (ushort*)ws;   ws += (size_t)H2 * H1 * 2;        // 8.4 MB
  ushort* Woutp = (ushort*)ws; ws += (size_t)CPAD * H2 * 2;      // 5.2 MB
  ushort* Eb = (ushort*)ws;    ws += (size_t)VOCAB * E * 2;      // 60 MB
  int* xT = (int*)ws;          ws += (size_t)S * BATCH * 4;      // 4 MB

  cvt_all<<<(NQ_TOT + 255) / 256, 256, 0, stream>>>(emb, Eb, W1, W1p, W2, W2b,
                                                    Wout, Woutp, x, xT);
  embed_kernel<<<BATCH, S, 0, stream>>>(xT, Eb, feat);

  // L1: feat[8192,640] x W1p[2048,640]^T -> relu -> h1[8192,2048] bf16
  gemm_bt<true, false, false><<<dim3(H1 / BN2, BATCH / BM2), 512, 0, stream>>>(
      feat, W1p, b1, (void*)h1, KPAD, KPAD, KPAD, H1, H1);
  // L2: h1 x W2b[2048,2048]^T -> relu -> h2 bf16
  gemm_bt<true, false, false><<<dim3(H2 / BN2, BATCH / BM2), 512, 0, stream>>>(
      h1, W2b, b2, (void*)h2, H1, H1, H1, H2, H2);
  // L3: h2 x Woutp[1280,2048]^T + bias -> out[8192,1221] fp32 (guarded)
  gemm_bt<false, true, true><<<dim3(CPAD / BN2, BATCH / BM2), 512, 0, stream>>>(
      h2, Woutp, bout, (void*)out, H2, H2, H2, CLS, CLS);
}